// Round 7
// baseline (698.217 us; speedup 1.0000x reference)
//
#include <hip/hip_runtime.h>
#include <hip/hip_bf16.h>
#include <stdint.h>

// Problem constants (fixed by setup_inputs)
#define T_TOK 8192
#define D_DIM 1024
#define H_DIM 2048
#define E_NUM 8
#define CAP   1280       // int(1.25 * T / E)
#define CAP2  2560       // per expert: [k=0: CAP slots][k=1: CAP slots]
#define MT_K  10         // M-tiles per (e,k) region: CAP/BM

#define BM 128
#define BN 128
#define BN_GU 64         // gateup N-tile per matrix (acc = 64 f32/thread)
#define BK 32

#define ROUTE_BLKS (T_TOK / 4)   // 2048 router blocks in prep_k
#define CONV_BLKS  4096          // conversion blocks in prep_k

typedef __attribute__((ext_vector_type(8))) short short8;   // 8 bf16 (4 VGPRs)
typedef __attribute__((ext_vector_type(4))) float float4v;  // MFMA C/D
typedef __attribute__((address_space(1))) const unsigned int gu32;
typedef __attribute__((address_space(3))) unsigned int lu32;

static __device__ __forceinline__ unsigned short f2bf(float f) {
    unsigned int u = __float_as_uint(f);
    unsigned int r = (u + 0x7FFFu + ((u >> 16) & 1u)) >> 16;  // RNE
    return (unsigned short)r;
}

static __device__ __forceinline__ void store4bf(unsigned short* d, float4 v) {
    union { unsigned short u[4]; uint2 q; } pk;
    pk.u[0] = f2bf(v.x); pk.u[1] = f2bf(v.y);
    pk.u[2] = f2bf(v.z); pk.u[3] = f2bf(v.w);
    *(uint2*)d = pk.q;
}

// ---------------------------------------------------------------------------
// prep_k: router (blocks 0..ROUTE_BLKS) and fp32->bf16 weight conversion
// (remaining CONV_BLKS) merged into ONE dispatch so the two independent
// pieces overlap instead of serializing on the stream.
// ---------------------------------------------------------------------------
__global__ __launch_bounds__(256) void prep_k(
    const float* __restrict__ x, const float* __restrict__ gw,
    int* __restrict__ topi, float* __restrict__ topw,
    unsigned short* __restrict__ xbf,
    const float* __restrict__ wg, const float* __restrict__ wu,
    const float* __restrict__ wd,
    unsigned short* __restrict__ wgbf, unsigned short* __restrict__ wubf,
    unsigned short* __restrict__ wdbf) {
    if (blockIdx.x < ROUTE_BLKS) {
        // ------- router: 4 waves/block, one wave per token; converts x->bf16
        const int t = blockIdx.x * 4 + (threadIdx.x >> 6);
        const int lane = threadIdx.x & 63;
        const float* xr = x + (size_t)t * D_DIM;
        unsigned short* xbr = xbf + (size_t)t * D_DIM;

        float p[E_NUM];
#pragma unroll
        for (int e = 0; e < E_NUM; ++e) p[e] = 0.f;
#pragma unroll
        for (int c = 0; c < 4; ++c) {
            const int idx = c * 256 + lane * 4;
            const float4 xv = *(const float4*)(xr + idx);
            store4bf(xbr + idx, xv);
#pragma unroll
            for (int e = 0; e < E_NUM; ++e) {
                const float4 gv = *(const float4*)(gw + e * D_DIM + idx);
                p[e] += xv.x * gv.x + xv.y * gv.y + xv.z * gv.z + xv.w * gv.w;
            }
        }
#pragma unroll
        for (int e = 0; e < E_NUM; ++e) {
            float v = p[e];
#pragma unroll
            for (int off = 32; off >= 1; off >>= 1) v += __shfl_xor(v, off);
            p[e] = v;
        }
        if (lane == 0) {
            float mx = p[0];
#pragma unroll
            for (int e = 1; e < E_NUM; ++e) mx = fmaxf(mx, p[e]);
            float pe[E_NUM]; float s = 0.f;
#pragma unroll
            for (int e = 0; e < E_NUM; ++e) { pe[e] = expf(p[e] - mx); s += pe[e]; }
            const float inv = 1.f / s;
            int i0 = 0;
#pragma unroll
            for (int e = 1; e < E_NUM; ++e) if (pe[e] > pe[i0]) i0 = e;
            int i1 = -1;
#pragma unroll
            for (int e = 0; e < E_NUM; ++e) {
                if (e == i0) continue;
                if (i1 < 0 || pe[e] > pe[i1]) i1 = e;
            }
            const float p0 = pe[i0] * inv, p1 = pe[i1] * inv;
            const float wn = 1.f / (p0 + p1 + 1e-9f);
            topi[t * 2 + 0] = i0; topi[t * 2 + 1] = i1;
            topw[t * 2 + 0] = p0 * wn; topw[t * 2 + 1] = p1 * wn;
        }
    } else {
        // ------- weight conversion: grid-stride over 3 tensors of float4s
        const int W4 = E_NUM * H_DIM * D_DIM / 4;   // 4,194,304 per weight
        const int total = 3 * W4;
        const int stride = CONV_BLKS * 256;
        for (int i = (blockIdx.x - ROUTE_BLKS) * 256 + threadIdx.x; i < total;
             i += stride) {
            const float* s; unsigned short* d; int j;
            if (i < W4)          { s = wg; d = wgbf; j = i; }
            else if (i < 2 * W4) { s = wu; d = wubf; j = i - W4; }
            else                 { s = wd; d = wdbf; j = i - 2 * W4; }
            store4bf(d + (size_t)j * 4, ((const float4*)s)[j]);
        }
    }
}

// ---------------------------------------------------------------------------
// Router-only kernel (legacy fallback path)
// ---------------------------------------------------------------------------
__global__ __launch_bounds__(256) void router_k(
    const float* __restrict__ x, const float* __restrict__ gw,
    int* __restrict__ topi, float* __restrict__ topw,
    unsigned short* __restrict__ xbf) {
    const int t = blockIdx.x * 4 + (threadIdx.x >> 6);
    const int lane = threadIdx.x & 63;
    const float* xr = x + (size_t)t * D_DIM;
    unsigned short* xbr = xbf + (size_t)t * D_DIM;

    float p[E_NUM];
#pragma unroll
    for (int e = 0; e < E_NUM; ++e) p[e] = 0.f;
#pragma unroll
    for (int c = 0; c < 4; ++c) {
        const int idx = c * 256 + lane * 4;
        const float4 xv = *(const float4*)(xr + idx);
        store4bf(xbr + idx, xv);
#pragma unroll
        for (int e = 0; e < E_NUM; ++e) {
            const float4 gv = *(const float4*)(gw + e * D_DIM + idx);
            p[e] += xv.x * gv.x + xv.y * gv.y + xv.z * gv.z + xv.w * gv.w;
        }
    }
#pragma unroll
    for (int e = 0; e < E_NUM; ++e) {
        float v = p[e];
#pragma unroll
        for (int off = 32; off >= 1; off >>= 1) v += __shfl_xor(v, off);
        p[e] = v;
    }
    if (lane == 0) {
        float mx = p[0];
#pragma unroll
        for (int e = 1; e < E_NUM; ++e) mx = fmaxf(mx, p[e]);
        float pe[E_NUM]; float s = 0.f;
#pragma unroll
        for (int e = 0; e < E_NUM; ++e) { pe[e] = expf(p[e] - mx); s += pe[e]; }
        const float inv = 1.f / s;
        int i0 = 0;
#pragma unroll
        for (int e = 1; e < E_NUM; ++e) if (pe[e] > pe[i0]) i0 = e;
        int i1 = -1;
#pragma unroll
        for (int e = 0; e < E_NUM; ++e) {
            if (e == i0) continue;
            if (i1 < 0 || pe[e] > pe[i1]) i1 = e;
        }
        const float p0 = pe[i0] * inv, p1 = pe[i1] * inv;
        const float wn = 1.f / (p0 + p1 + 1e-9f);
        topi[t * 2 + 0] = i0; topi[t * 2 + 1] = i1;
        topw[t * 2 + 0] = p0 * wn; topw[t * 2 + 1] = p1 * wn;
    }
}

// ---------------------------------------------------------------------------
// Assignment: one block, 16 waves; wave (k,e) scans tokens in order.
// Layout: expert e slots = [k=0: e*CAP2 + 0..CAP) [k=1: e*CAP2+CAP ..).
// cnt[e*2+k] = kept count per (e,k). Pad slots: tok=0, w=0 (masked in down).
// ---------------------------------------------------------------------------
__global__ __launch_bounds__(1024) void assign_k(
    const int* __restrict__ topi, const float* __restrict__ topw,
    int* __restrict__ tok_list, float* __restrict__ w_list,
    int* __restrict__ cnt) {
    __shared__ unsigned char topiL[T_TOK * 2];   // 16 KB
    __shared__ int kept[2][E_NUM];
    const int tid = threadIdx.x;
    const int wid = tid >> 6, lane = tid & 63;
    const int k = wid >> 3, e = wid & 7;
    const uint64_t lt = (1ull << lane) - 1ull;

    for (int i = tid; i < T_TOK * 2 / 4; i += 1024) {
        const int4 v = ((const int4*)topi)[i];
        uchar4 b;
        b.x = (unsigned char)v.x; b.y = (unsigned char)v.y;
        b.z = (unsigned char)v.z; b.w = (unsigned char)v.w;
        ((uchar4*)topiL)[i] = b;
    }
    __syncthreads();

    // phase 1: total per-(k,e) counts
    int total = 0;
    for (int base = 0; base < T_TOK; base += 64) {
        const int idx = topiL[(base + lane) * 2 + k];
        total += __popcll(__ballot(idx == e));
    }
    if (lane == 0) {
        const int kc = min(total, CAP);
        kept[k][e] = kc;
        cnt[e * 2 + k] = kc;
    }
    __syncthreads();
    const int myBase = e * CAP2 + k * CAP;

    // phase 2: ordered compaction of kept tokens
    int running = 0, keptRun = 0;
    for (int base = 0; base < T_TOK; base += 64) {
        const int t = base + lane;
        const bool pred = (topiL[t * 2 + k] == e);
        const uint64_t m = __ballot(pred);
        const int rank = running + __popcll(m & lt);
        const bool keep = pred && (rank < CAP);
        const uint64_t km = __ballot(keep);
        if (keep) {
            const int slot = myBase + keptRun + __popcll(km & lt);
            tok_list[slot] = t;
            w_list[slot] = topw[t * 2 + k];
        }
        running += __popcll(m);
        keptRun += __popcll(km);
    }
    __syncthreads();
    // phase 3: pad unused slots (safe token 0, zero weight)
    for (int s = tid; s < E_NUM * CAP2; s += 1024) {
        const int ee = s / CAP2;
        const int rem = s - ee * CAP2;
        const int kk = rem / CAP, ls = rem - kk * CAP;
        if (ls >= kept[kk][ee]) { tok_list[s] = 0; w_list[s] = 0.f; }
    }
}

// ---------------------------------------------------------------------------
// Fused gate+up GEMM, bf16. BM=128, BN_GU=64 per matrix.
// BK=64 with XOR chunk swizzle: conflict-free ds_read_b128 (round-2/5
// verified: SQ_LDS_BANK_CONFLICT = 0). 32 KB LDS, 4 blocks/CU.
// Epilogue: direct 2B stores (round-5 verified; LDS-staged variant regressed).
// ---------------------------------------------------------------------------
__global__ __launch_bounds__(256, 4) void gateup_bf_k(
    const unsigned short* __restrict__ xbf,
    const unsigned short* __restrict__ wgbf, const unsigned short* __restrict__ wubf,
    const int* __restrict__ tok_list, const int* __restrict__ cnt,
    unsigned short* __restrict__ h_ws, int e0) {
    const int ez = blockIdx.z;
    const int e = e0 + ez;
    const int kk = blockIdx.y / MT_K;
    const int m0 = (blockIdx.y - kk * MT_K) * BM;
    if (m0 >= cnt[e * 2 + kk]) return;
    const int n0 = blockIdx.x * BN_GU;
    const int sbase = e * CAP2 + kk * CAP + m0;           // global slot base
    const size_t hbase = (size_t)ez * CAP2 + kk * CAP + m0;

    // A: 128x64 (16 KB) | Bg: 64x64 (8 KB) | Bu: 64x64 (8 KB) = 32 KB
    __shared__ __align__(1024) unsigned short smem[16384];

    const int tid = threadIdx.x, wid = tid >> 6, lane = tid & 63;

    const unsigned short* gsrc[8];
    int ldsoff[8];
#pragma unroll
    for (int i = 0; i < 8; ++i) {
        const int f = (wid * 8 + i) * 64 + lane;   // 16B slot index, 0..2047
        const unsigned short* g;
        if (f < 1024) {                  // A: 128 rows x 8 chunks, swizzled
            const int r = f >> 3, c = (f & 7) ^ (r & 7);
            const int tok = tok_list[sbase + r];
            g = xbf + (size_t)tok * D_DIM + c * 8;
        } else if (f < 1536) {           // Bg: 64 rows x 8 chunks, swizzled
            const int fr = f - 1024;
            const int r = fr >> 3, c = (fr & 7) ^ (r & 7);
            g = wgbf + ((size_t)e * H_DIM + n0 + r) * D_DIM + c * 8;
        } else {                         // Bu: 64 rows x 8 chunks, swizzled
            const int fr = f - 1536;
            const int r = fr >> 3, c = (fr & 7) ^ (r & 7);
            g = wubf + ((size_t)e * H_DIM + n0 + r) * D_DIM + c * 8;
        }
        gsrc[i] = g;
        ldsoff[i] = (wid * 8 + i) * 1024;   // bytes, wave-uniform
    }

    float4v accg[4][2], accu[4][2];
#pragma unroll
    for (int i = 0; i < 4; ++i)
#pragma unroll
        for (int j = 0; j < 2; ++j) {
            accg[i][j] = (float4v){0.f, 0.f, 0.f, 0.f};
            accu[i][j] = (float4v){0.f, 0.f, 0.f, 0.f};
        }

    const int wm = (wid & 1) * 64;       // wave M-offset: 2 waves over 128 rows
    const int wn = (wid >> 1) * 32;      // wave N-offset: 2 waves over 64 cols
    const int frow = lane & 15;
    const int quad = lane >> 4;

    for (int k0 = 0; k0 < D_DIM; k0 += 64) {
#pragma unroll
        for (int i = 0; i < 8; ++i)
            __builtin_amdgcn_global_load_lds(
                (gu32*)(gsrc[i] + k0),
                (lu32*)((char*)smem + ldsoff[i]), 16, 0, 0);
        __syncthreads();

#pragma unroll
        for (int s = 0; s < 2; ++s) {
            const int c = s * 4 + quad;           // chunk: k = s*32 + quad*8
            short8 af[4], bgf[2], buf[2];
#pragma unroll
            for (int i = 0; i < 4; ++i) {
                const int row = wm + i * 16 + frow;
                af[i] = *(const short8*)&smem[(row * 8 + (c ^ (row & 7))) * 8];
            }
#pragma unroll
            for (int j = 0; j < 2; ++j) {
                const int row = wn + j * 16 + frow;
                bgf[j] = *(const short8*)&smem[8192 + (row * 8 + (c ^ (row & 7))) * 8];
                buf[j] = *(const short8*)&smem[12288 + (row * 8 + (c ^ (row & 7))) * 8];
            }
#pragma unroll
            for (int i = 0; i < 4; ++i)
#pragma unroll
                for (int j = 0; j < 2; ++j) {
                    accg[i][j] = __builtin_amdgcn_mfma_f32_16x16x32_bf16(af[i], bgf[j], accg[i][j], 0, 0, 0);
                    accu[i][j] = __builtin_amdgcn_mfma_f32_16x16x32_bf16(af[i], buf[j], accu[i][j], 0, 0, 0);
                }
        }
        __syncthreads();
    }

    const int col = lane & 15, rbase = (lane >> 4) * 4;
#pragma unroll
    for (int i = 0; i < 4; ++i)
#pragma unroll
        for (int j = 0; j < 2; ++j)
#pragma unroll
            for (int r = 0; r < 4; ++r) {
                const float g = accg[i][j][r];
                const float u = accu[i][j][r];
                const float hv = (g / (1.f + __expf(-g))) * u;
                const int m = wm + i * 16 + rbase + r;
                const int n = wn + j * 16 + col;
                h_ws[(hbase + m) * H_DIM + (n0 + n)] = f2bf(hv);
            }
}

// ---------------------------------------------------------------------------
// Down GEMM, SPLIT-BUFFER merged form: ONE dispatch over both k-regions
// (z = 2*ne, kk = z&1). kk=0 blocks plain-store to out; kk=1 blocks
// plain-store to out2 (both pre-zeroed). No atomics, race-free by
// construction. combine_k adds out2 into out afterwards.
// THIS ROUND's single change: __launch_bounds__(256,3) -> (256,4) — down was
// the only GEMM still at 3 blocks/CU (gateup's r1 occupancy lever: 2->3 was
// -12%). LDS 33 KB x 4 = 132 KB < 160 KB; register profile matches gateup's
// bounds-4 build (VGPR 64).
// BK=64 with XOR chunk swizzle (global_load_lds forbids padding, m104/m108).
// ---------------------------------------------------------------------------
__global__ __launch_bounds__(256, 4) void down_split_bf_k(
    const unsigned short* __restrict__ h_ws, const unsigned short* __restrict__ wdbf,
    const int* __restrict__ tok_list, const float* __restrict__ w_list,
    const int* __restrict__ cnt, float* __restrict__ out,
    float* __restrict__ out2, int e0) {
    const int ez = blockIdx.z >> 1;
    const int kk = blockIdx.z & 1;
    const int e = e0 + ez;
    const int m0 = blockIdx.y * BM;
    const int nkept = cnt[e * 2 + kk];
    if (m0 >= nkept) return;
    const int n0 = blockIdx.x * BN;
    const int sbase = e * CAP2 + kk * CAP + m0;
    const size_t hbase = (size_t)ez * CAP2 + kk * CAP + m0;

    __shared__ __align__(1024) unsigned short smem[16384];   // 32 KB: A|B
    __shared__ int tokL[BM];
    __shared__ float wL[BM];

    const int tid = threadIdx.x, wid = tid >> 6, lane = tid & 63;
    if (tid < BM) {
        tokL[tid] = tok_list[sbase + tid];
        wL[tid] = w_list[sbase + tid];
    }

    const unsigned short* gsrc[8];
    int ldsoff[8];
#pragma unroll
    for (int i = 0; i < 8; ++i) {
        const int f = (wid * 8 + i) * 64 + lane;   // 16B slot index, 0..2047
        const unsigned short* g;
        if (f < 1024) {          // A region: h rows, 128 rows x 8 chunks
            const int r = f >> 3, c = (f & 7) ^ (r & 7);
            g = h_ws + (hbase + r) * H_DIM + c * 8;
        } else {                 // B region: wd rows
            const int fr = f - 1024;
            const int r = fr >> 3, c = (fr & 7) ^ (r & 7);
            g = wdbf + ((size_t)e * D_DIM + n0 + r) * H_DIM + c * 8;
        }
        gsrc[i] = g;
        ldsoff[i] = (wid * 8 + i) * 1024;   // bytes, wave-uniform
    }

    float4v acc[4][4];
#pragma unroll
    for (int i = 0; i < 4; ++i)
#pragma unroll
        for (int j = 0; j < 4; ++j) acc[i][j] = (float4v){0.f, 0.f, 0.f, 0.f};

    const int wm = (wid & 1) * 64, wn = (wid >> 1) * 64;
    const int frow = lane & 15;
    const int quad = lane >> 4;

    for (int k0 = 0; k0 < H_DIM; k0 += 64) {
#pragma unroll
        for (int i = 0; i < 8; ++i)
            __builtin_amdgcn_global_load_lds(
                (gu32*)(gsrc[i] + k0),
                (lu32*)((char*)smem + ldsoff[i]), 16, 0, 0);
        __syncthreads();

#pragma unroll
        for (int s = 0; s < 2; ++s) {
            const int c = s * 4 + quad;
            short8 af[4], bf[4];
#pragma unroll
            for (int i = 0; i < 4; ++i) {
                const int row = wm + i * 16 + frow;
                af[i] = *(const short8*)&smem[(row * 8 + (c ^ (row & 7))) * 8];
            }
#pragma unroll
            for (int j = 0; j < 4; ++j) {
                const int row = wn + j * 16 + frow;
                bf[j] = *(const short8*)&smem[8192 + (row * 8 + (c ^ (row & 7))) * 8];
            }
#pragma unroll
            for (int i = 0; i < 4; ++i)
#pragma unroll
                for (int j = 0; j < 4; ++j)
                    acc[i][j] = __builtin_amdgcn_mfma_f32_16x16x32_bf16(af[i], bf[j], acc[i][j], 0, 0, 0);
        }
        __syncthreads();
    }

    // Epilogue: plain stores to the kk-selected buffer; pad rows masked.
    float* dbuf = kk ? out2 : out;
    const int col = lane & 15, rbase = (lane >> 4) * 4;
#pragma unroll
    for (int i = 0; i < 4; ++i)
#pragma unroll
        for (int r = 0; r < 4; ++r) {
            const int m = wm + i * 16 + rbase + r;
            if (m0 + m >= nkept) continue;       // pad row: skip
            const float wRow = wL[m];
            float* orow = dbuf + (size_t)tokL[m] * D_DIM + n0;
#pragma unroll
            for (int j = 0; j < 4; ++j) {
                const int n = j * 16 + wn + col;
                orow[n] = acc[i][j][r] * wRow;
            }
        }
}

// combine: out += out2 (float4 grid-stride, ~100 MB traffic)
__global__ __launch_bounds__(256) void combine_k(
    float* __restrict__ out, const float* __restrict__ out2) {
    const int total = T_TOK * D_DIM / 4;   // 2,097,152 float4s
    const int stride = gridDim.x * 256;
    for (int i = blockIdx.x * 256 + threadIdx.x; i < total; i += stride) {
        float4 a = ((float4*)out)[i];
        const float4 b = ((const float4*)out2)[i];
        a.x += b.x; a.y += b.y; a.z += b.z; a.w += b.w;
        ((float4*)out)[i] = a;
    }
}

// ---------------------------------------------------------------------------
// Down GEMM two-pass form (round-5 verified fallback when out2 doesn't fit).
// Pass kk=0: plain stores. Pass kk=1: load-add-store. Pad rows masked.
// ---------------------------------------------------------------------------
__global__ __launch_bounds__(256, 3) void down_bf_k(
    const unsigned short* __restrict__ h_ws, const unsigned short* __restrict__ wdbf,
    const int* __restrict__ tok_list, const float* __restrict__ w_list,
    const int* __restrict__ cnt, float* __restrict__ out, int e0, int kk) {
    const int ez = blockIdx.z;
    const int e = e0 + ez;
    const int m0 = blockIdx.y * BM;
    const int nkept = cnt[e * 2 + kk];
    if (m0 >= nkept) return;
    const int n0 = blockIdx.x * BN;
    const int sbase = e * CAP2 + kk * CAP + m0;
    const size_t hbase = (size_t)ez * CAP2 + kk * CAP + m0;

    __shared__ __align__(1024) unsigned short smem[16384];   // 32 KB: A|B
    __shared__ int tokL[BM];
    __shared__ float wL[BM];

    const int tid = threadIdx.x, wid = tid >> 6, lane = tid & 63;
    if (tid < BM) {
        tokL[tid] = tok_list[sbase + tid];
        wL[tid] = w_list[sbase + tid];
    }

    const unsigned short* gsrc[8];
    int ldsoff[8];
#pragma unroll
    for (int i = 0; i < 8; ++i) {
        const int f = (wid * 8 + i) * 64 + lane;   // 16B slot index, 0..2047
        const unsigned short* g;
        if (f < 1024) {          // A region: h rows, 128 rows x 8 chunks
            const int r = f >> 3, c = (f & 7) ^ (r & 7);
            g = h_ws + (hbase + r) * H_DIM + c * 8;
        } else {                 // B region: wd rows
            const int fr = f - 1024;
            const int r = fr >> 3, c = (fr & 7) ^ (r & 7);
            g = wdbf + ((size_t)e * D_DIM + n0 + r) * H_DIM + c * 8;
        }
        gsrc[i] = g;
        ldsoff[i] = (wid * 8 + i) * 1024;   // bytes, wave-uniform
    }

    float4v acc[4][4];
#pragma unroll
    for (int i = 0; i < 4; ++i)
#pragma unroll
        for (int j = 0; j < 4; ++j) acc[i][j] = (float4v){0.f, 0.f, 0.f, 0.f};

    const int wm = (wid & 1) * 64, wn = (wid >> 1) * 64;
    const int frow = lane & 15;
    const int quad = lane >> 4;

    for (int k0 = 0; k0 < H_DIM; k0 += 64) {
#pragma unroll
        for (int i = 0; i < 8; ++i)
            __builtin_amdgcn_global_load_lds(
                (gu32*)(gsrc[i] + k0),
                (lu32*)((char*)smem + ldsoff[i]), 16, 0, 0);
        __syncthreads();

#pragma unroll
        for (int s = 0; s < 2; ++s) {
            const int c = s * 4 + quad;
            short8 af[4], bf[4];
#pragma unroll
            for (int i = 0; i < 4; ++i) {
                const int row = wm + i * 16 + frow;
                af[i] = *(const short8*)&smem[(row * 8 + (c ^ (row & 7))) * 8];
            }
#pragma unroll
            for (int j = 0; j < 4; ++j) {
                const int row = wn + j * 16 + frow;
                bf[j] = *(const short8*)&smem[8192 + (row * 8 + (c ^ (row & 7))) * 8];
            }
#pragma unroll
            for (int i = 0; i < 4; ++i)
#pragma unroll
                for (int j = 0; j < 4; ++j)
                    acc[i][j] = __builtin_amdgcn_mfma_f32_16x16x32_bf16(af[i], bf[j], acc[i][j], 0, 0, 0);
        }
        __syncthreads();
    }

    // Epilogue: plain store (kk=0) or load-add-store (kk=1); pad rows masked.
    const int col = lane & 15, rbase = (lane >> 4) * 4;
#pragma unroll
    for (int i = 0; i < 4; ++i)
#pragma unroll
        for (int r = 0; r < 4; ++r) {
            const int m = wm + i * 16 + rbase + r;
            if (m0 + m >= nkept) continue;       // pad row: skip (avoid races)
            const float wRow = wL[m];
            float* orow = out + (size_t)tokL[m] * D_DIM + n0;
#pragma unroll
            for (int j = 0; j < 4; ++j) {
                const int n = j * 16 + wn + col;
                const float v = acc[i][j][r] * wRow;
                if (kk == 0) orow[n] = v;
                else         orow[n] += v;
            }
        }
}

// ---------------------------------------------------------------------------
// Legacy fp32-staging kernels (fallback if workspace too small for bf16 path)
// ---------------------------------------------------------------------------
__global__ __launch_bounds__(256, 2) void gateup_legacy_k(
    const float* __restrict__ x,
    const float* __restrict__ wg_all, const float* __restrict__ wu_all,
    const int* __restrict__ tok_list, const int* __restrict__ cnt,
    unsigned short* __restrict__ h_ws, int e0) {
    const int ez = blockIdx.z;
    const int e = e0 + ez;
    const int kk = blockIdx.y / MT_K;
    const int m0 = (blockIdx.y - kk * MT_K) * BM;
    if (m0 >= cnt[e * 2 + kk]) return;
    const int n0 = blockIdx.x * BN;
    const int sbase = e * CAP2 + kk * CAP + m0;
    const size_t hbase = (size_t)ez * CAP2 + kk * CAP + m0;

    __shared__ __align__(16) unsigned short As[BM][BK];
    __shared__ __align__(16) unsigned short Bg[BN][BK];
    __shared__ __align__(16) unsigned short Bu[BN][BK];
    __shared__ int tokL[BM];

    const int tid = threadIdx.x;
    if (tid < BM) tokL[tid] = tok_list[sbase + tid];
    __syncthreads();

    const float* wg = wg_all + (size_t)e * H_DIM * D_DIM;
    const float* wu = wu_all + (size_t)e * H_DIM * D_DIM;

    const float* aSrc[4]; const float* gSrc[4]; const float* uSrc[4];
    unsigned short* aDst[4]; unsigned short* gDst[4]; unsigned short* uDst[4];
#pragma unroll
    for (int it = 0; it < 4; ++it) {
        const int fid = it * 256 + tid;
        const int row = fid >> 3;
        const int c4 = (fid & 7) * 4;
        aSrc[it] = x + (size_t)tokL[row] * D_DIM + c4;
        gSrc[it] = wg + (size_t)(n0 + row) * D_DIM + c4;
        uSrc[it] = wu + (size_t)(n0 + row) * D_DIM + c4;
        aDst[it] = &As[row][c4];
        gDst[it] = &Bg[row][c4];
        uDst[it] = &Bu[row][c4];
    }

    float4v accg[4][4], accu[4][4];
#pragma unroll
    for (int i = 0; i < 4; ++i)
#pragma unroll
        for (int j = 0; j < 4; ++j) {
            accg[i][j] = (float4v){0.f, 0.f, 0.f, 0.f};
            accu[i][j] = (float4v){0.f, 0.f, 0.f, 0.f};
        }

    const int wid = tid >> 6, lane = tid & 63;
    const int wm = (wid & 1) * 64, wn = (wid >> 1) * 64;
    const int frow = lane & 15;
    const int fk = (lane >> 4) * 8;

    for (int k0 = 0; k0 < D_DIM; k0 += BK) {
#pragma unroll
        for (int it = 0; it < 4; ++it) {
            store4bf(aDst[it], *(const float4*)(aSrc[it] + k0));
            store4bf(gDst[it], *(const float4*)(gSrc[it] + k0));
            store4bf(uDst[it], *(const float4*)(uSrc[it] + k0));
        }
        __syncthreads();
        short8 af[4], bgf[4], buf[4];
#pragma unroll
        for (int i = 0; i < 4; ++i)
            af[i] = *(const short8*)&As[wm + i * 16 + frow][fk];
#pragma unroll
        for (int j = 0; j < 4; ++j) {
            bgf[j] = *(const short8*)&Bg[wn + j * 16 + frow][fk];
            buf[j] = *(const short8*)&Bu[wn + j * 16 + frow][fk];
        }
#pragma unroll
        for (int i = 0; i < 4; ++i)
#pragma unroll
            for (int j = 0; j < 4; ++j) {
                accg[i][j] = __builtin_amdgcn_mfma_f32_16x16x32_bf16(af[i], bgf[j], accg[i][j], 0, 0, 0);
                accu[i][j] = __builtin_amdgcn_mfma_f32_16x16x32_bf16(af[i], buf[j], accu[i][j], 0, 0, 0);
            }
        __syncthreads();
    }

    const int col = lane & 15, rbase = (lane >> 4) * 4;
#pragma unroll
    for (int i = 0; i < 4; ++i)
#pragma unroll
        for (int j = 0; j < 4; ++j)
#pragma unroll
            for (int r = 0; r < 4; ++r) {
                const float g = accg[i][j][r];
                const float u = accu[i][j][r];
                const float hv = (g / (1.f + __expf(-g))) * u;
                const int m = wm + i * 16 + rbase + r;
                const int n = wn + j * 16 + col;
                h_ws[(hbase + m) * H_DIM + (n0 + n)] = f2bf(hv);
            }
}

__global__ __launch_bounds__(256, 2) void down_legacy_k(
    const unsigned short* __restrict__ h_ws, const float* __restrict__ wd_all,
    const int* __restrict__ tok_list, const float* __restrict__ w_list,
    const int* __restrict__ cnt, float* __restrict__ out, int e0) {
    const int ez = blockIdx.z;
    const int e = e0 + ez;
    const int kk = blockIdx.y / MT_K;
    const int m0 = (blockIdx.y - kk * MT_K) * BM;
    if (m0 >= cnt[e * 2 + kk]) return;
    const int n0 = blockIdx.x * BN;
    const int sbase = e * CAP2 + kk * CAP + m0;
    const size_t hbase = (size_t)ez * CAP2 + kk * CAP + m0;

    __shared__ __align__(16) unsigned short As[BM][BK];
    __shared__ __align__(16) unsigned short Bs[BN][BK];
    __shared__ int tokL[BM];
    __shared__ float wL[BM];

    const int tid = threadIdx.x;
    if (tid < BM) {
        tokL[tid] = tok_list[sbase + tid];
        wL[tid] = w_list[sbase + tid];
    }
    __syncthreads();

    const unsigned short* hA = h_ws + hbase * H_DIM;
    const float* wd = wd_all + (size_t)e * D_DIM * H_DIM;

    const unsigned short* aSrc[2]; unsigned short* aDst[2];
#pragma unroll
    for (int it = 0; it < 2; ++it) {
        const int fid = it * 256 + tid;
        const int row = fid >> 2;
        const int c8 = (fid & 3) * 8;
        aSrc[it] = hA + (size_t)row * H_DIM + c8;
        aDst[it] = &As[row][c8];
    }
    const float* bSrc[4]; unsigned short* bDst[4];
#pragma unroll
    for (int it = 0; it < 4; ++it) {
        const int fid = it * 256 + tid;
        const int row = fid >> 3;
        const int c4 = (fid & 7) * 4;
        bSrc[it] = wd + (size_t)(n0 + row) * H_DIM + c4;
        bDst[it] = &Bs[row][c4];
    }

    float4v acc[4][4];
#pragma unroll
    for (int i = 0; i < 4; ++i)
#pragma unroll
        for (int j = 0; j < 4; ++j) acc[i][j] = (float4v){0.f, 0.f, 0.f, 0.f};

    const int wid = tid >> 6, lane = tid & 63;
    const int wm = (wid & 1) * 64, wn = (wid >> 1) * 64;
    const int frow = lane & 15;
    const int fk = (lane >> 4) * 8;

    for (int k0 = 0; k0 < H_DIM; k0 += BK) {
#pragma unroll
        for (int it = 0; it < 2; ++it)
            *(uint4*)aDst[it] = *(const uint4*)(aSrc[it] + k0);
#pragma unroll
        for (int it = 0; it < 4; ++it)
            store4bf(bDst[it], *(const float4*)(bSrc[it] + k0));
        __syncthreads();
        short8 af[4], bf[4];
#pragma unroll
        for (int i = 0; i < 4; ++i)
            af[i] = *(const short8*)&As[wm + i * 16 + frow][fk];
#pragma unroll
        for (int j = 0; j < 4; ++j)
            bf[j] = *(const short8*)&Bs[wn + j * 16 + frow][fk];
#pragma unroll
        for (int i = 0; i < 4; ++i)
#pragma unroll
            for (int j = 0; j < 4; ++j)
                acc[i][j] = __builtin_amdgcn_mfma_f32_16x16x32_bf16(af[i], bf[j], acc[i][j], 0, 0, 0);
        __syncthreads();
    }

    const int col = lane & 15, rbase = (lane >> 4) * 4;
#pragma unroll
    for (int i = 0; i < 4; ++i)
#pragma unroll
        for (int j = 0; j < 4; ++j)
#pragma unroll
            for (int r = 0; r < 4; ++r) {
                const int m = wm + i * 16 + rbase + r;
                const int n = wn + j * 16 + col;
                const float v = acc[i][j][r] * wL[m];
                unsafeAtomicAdd(&out[(size_t)tokL[m] * D_DIM + n0 + n], v);
            }
}

// ---------------------------------------------------------------------------
extern "C" void kernel_launch(void* const* d_in, const int* in_sizes, int n_in,
                              void* d_out, int out_size, void* d_ws, size_t ws_size,
                              hipStream_t stream) {
    const float* x        = (const float*)d_in[0];
    const float* gate_w   = (const float*)d_in[1];
    const float* gate_pw  = (const float*)d_in[2];
    const float* up_pw    = (const float*)d_in[3];
    const float* down_pw  = (const float*)d_in[4];
    float* out = (float*)d_out;
    (void)n_in; (void)in_sizes; (void)out_size;

    uint8_t* ws = (uint8_t*)d_ws;
    size_t off = 0;
    int*   topi     = (int*)(ws + off);   off += (size_t)T_TOK * 2 * 4;
    float* topw     = (float*)(ws + off); off += (size_t)T_TOK * 2 * 4;
    int*   tok_list = (int*)(ws + off);   off += (size_t)E_NUM * CAP2 * 4;
    float* w_list   = (float*)(ws + off); off += (size_t)E_NUM * CAP2 * 4;
    int*   cnt      = (int*)(ws + off);   off += 256;
    off = (off + 4095) & ~(size_t)4095;
    const size_t routing_end = off;

    const size_t x_elems = (size_t)T_TOK * D_DIM;           // 8.4 M
    const size_t w_elems = (size_t)E_NUM * H_DIM * D_DIM;   // 16.8 M each
    unsigned short* xbf  = (unsigned short*)(ws + off); off += x_elems * 2;
    unsigned short* wgbf = (unsigned short*)(ws + off); off += w_elems * 2;
    unsigned short* wubf = (unsigned short*)(ws + off); off += w_elems * 2;
    unsigned short* wdbf = (unsigned short*)(ws + off); off += w_elems * 2;
    const size_t need_base = off;                           // ~118 MB
    const size_t out2_sz = (size_t)T_TOK * D_DIM * 4;       // 33.5 MB
    const size_t per_e = (size_t)CAP2 * H_DIM * 2;          // 10.5 MB / expert

    hipMemsetAsync(out, 0, (size_t)T_TOK * D_DIM * sizeof(float), stream);

    if (ws_size >= need_base + out2_sz + per_e) {
        // bf16 fast path with split-buffer merged down
        float* out2 = (float*)(ws + need_base);
        unsigned short* h_ws = (unsigned short*)(ws + need_base + out2_sz);
        int chunk = (int)((ws_size - need_base - out2_sz) / per_e);
        if (chunk > E_NUM) chunk = E_NUM;

        hipMemsetAsync(out2, 0, out2_sz, stream);
        prep_k<<<ROUTE_BLKS + CONV_BLKS, 256, 0, stream>>>(
            x, gate_w, topi, topw, xbf,
            gate_pw, up_pw, down_pw, wgbf, wubf, wdbf);
        assign_k<<<1, 1024, 0, stream>>>(topi, topw, tok_list, w_list, cnt);

        for (int e0 = 0; e0 < E_NUM; e0 += chunk) {
            const int ne = (e0 + chunk <= E_NUM) ? chunk : (E_NUM - e0);
            dim3 g1(H_DIM / BN_GU, 2 * MT_K, ne);
            gateup_bf_k<<<g1, 256, 0, stream>>>(xbf, wgbf, wubf, tok_list, cnt, h_ws, e0);
            dim3 g2(D_DIM / BN, MT_K, 2 * ne);
            down_split_bf_k<<<g2, 256, 0, stream>>>(h_ws, wdbf, tok_list, w_list,
                                                    cnt, out, out2, e0);
        }
        combine_k<<<2048, 256, 0, stream>>>(out, out2);
    } else if (ws_size >= need_base + per_e) {
        // bf16 path, two-pass down (round-5 verified) when out2 doesn't fit
        unsigned short* h_ws = (unsigned short*)(ws + need_base);
        int chunk = (int)((ws_size - need_base) / per_e);
        if (chunk > E_NUM) chunk = E_NUM;

        prep_k<<<ROUTE_BLKS + CONV_BLKS, 256, 0, stream>>>(
            x, gate_w, topi, topw, xbf,
            gate_pw, up_pw, down_pw, wgbf, wubf, wdbf);
        assign_k<<<1, 1024, 0, stream>>>(topi, topw, tok_list, w_list, cnt);

        for (int e0 = 0; e0 < E_NUM; e0 += chunk) {
            const int ne = (e0 + chunk <= E_NUM) ? chunk : (E_NUM - e0);
            dim3 g1(H_DIM / BN_GU, 2 * MT_K, ne);
            gateup_bf_k<<<g1, 256, 0, stream>>>(xbf, wgbf, wubf, tok_list, cnt, h_ws, e0);
            dim3 g2(D_DIM / BN, MT_K, ne);
            down_bf_k<<<g2, 256, 0, stream>>>(h_ws, wdbf, tok_list, w_list, cnt, out, e0, 0);
            down_bf_k<<<g2, 256, 0, stream>>>(h_ws, wdbf, tok_list, w_list, cnt, out, e0, 1);
        }
    } else {
        // legacy fp32-staging path (small workspace)
        unsigned short* h_ws = (unsigned short*)(ws + routing_end);
        int chunk = (ws_size > routing_end) ? (int)((ws_size - routing_end) / per_e) : 0;
        if (chunk > E_NUM) chunk = E_NUM;
        if (chunk < 1) chunk = 1;

        router_k<<<T_TOK / 4, 256, 0, stream>>>(x, gate_w, topi, topw, xbf);
        assign_k<<<1, 1024, 0, stream>>>(topi, topw, tok_list, w_list, cnt);

        for (int e0 = 0; e0 < E_NUM; e0 += chunk) {
            const int ne = (e0 + chunk <= E_NUM) ? chunk : (E_NUM - e0);
            dim3 g1(H_DIM / BN, 2 * MT_K, ne);
            gateup_legacy_k<<<g1, 256, 0, stream>>>(x, gate_pw, up_pw, tok_list, cnt, h_ws, e0);
            dim3 g2(D_DIM / BN, 2 * MT_K, ne);
            down_legacy_k<<<g2, 256, 0, stream>>>(h_ws, down_pw, tok_list, w_list, cnt, out, e0);
        }
    }
}

// Round 8
// 591.013 us; speedup vs baseline: 1.1814x; 1.1814x over previous
//
#include <hip/hip_runtime.h>
#include <hip/hip_bf16.h>
#include <stdint.h>

// Problem constants (fixed by setup_inputs)
#define T_TOK 8192
#define D_DIM 1024
#define H_DIM 2048
#define E_NUM 8
#define CAP   1280       // int(1.25 * T / E)
#define CAP2  2560       // per expert: [k=0: CAP slots][k=1: CAP slots]
#define MT_K  10         // M-tiles per (e,k) region: CAP/BM

#define BM 128
#define BN 128
#define BN_GU 64         // gateup N-tile per matrix (acc = 64 f32/thread)
#define BK 32

#define ROUTE_BLKS (T_TOK / 4)   // 2048 router blocks in prep_k
#define CONV_BLKS  4096          // conversion blocks in prep_k

typedef __attribute__((ext_vector_type(8))) short short8;   // 8 bf16 (4 VGPRs)
typedef __attribute__((ext_vector_type(4))) float float4v;  // MFMA C/D
typedef __attribute__((address_space(1))) const unsigned int gu32;
typedef __attribute__((address_space(3))) unsigned int lu32;

static __device__ __forceinline__ unsigned short f2bf(float f) {
    unsigned int u = __float_as_uint(f);
    unsigned int r = (u + 0x7FFFu + ((u >> 16) & 1u)) >> 16;  // RNE
    return (unsigned short)r;
}

static __device__ __forceinline__ void store4bf(unsigned short* d, float4 v) {
    union { unsigned short u[4]; uint2 q; } pk;
    pk.u[0] = f2bf(v.x); pk.u[1] = f2bf(v.y);
    pk.u[2] = f2bf(v.z); pk.u[3] = f2bf(v.w);
    *(uint2*)d = pk.q;
}

// ---------------------------------------------------------------------------
// prep_k: router (blocks 0..ROUTE_BLKS) and fp32->bf16 weight conversion
// (remaining CONV_BLKS) merged into ONE dispatch so the two independent
// pieces overlap instead of serializing on the stream.
// ---------------------------------------------------------------------------
__global__ __launch_bounds__(256) void prep_k(
    const float* __restrict__ x, const float* __restrict__ gw,
    int* __restrict__ topi, float* __restrict__ topw,
    unsigned short* __restrict__ xbf,
    const float* __restrict__ wg, const float* __restrict__ wu,
    const float* __restrict__ wd,
    unsigned short* __restrict__ wgbf, unsigned short* __restrict__ wubf,
    unsigned short* __restrict__ wdbf) {
    if (blockIdx.x < ROUTE_BLKS) {
        // ------- router: 4 waves/block, one wave per token; converts x->bf16
        const int t = blockIdx.x * 4 + (threadIdx.x >> 6);
        const int lane = threadIdx.x & 63;
        const float* xr = x + (size_t)t * D_DIM;
        unsigned short* xbr = xbf + (size_t)t * D_DIM;

        float p[E_NUM];
#pragma unroll
        for (int e = 0; e < E_NUM; ++e) p[e] = 0.f;
#pragma unroll
        for (int c = 0; c < 4; ++c) {
            const int idx = c * 256 + lane * 4;
            const float4 xv = *(const float4*)(xr + idx);
            store4bf(xbr + idx, xv);
#pragma unroll
            for (int e = 0; e < E_NUM; ++e) {
                const float4 gv = *(const float4*)(gw + e * D_DIM + idx);
                p[e] += xv.x * gv.x + xv.y * gv.y + xv.z * gv.z + xv.w * gv.w;
            }
        }
#pragma unroll
        for (int e = 0; e < E_NUM; ++e) {
            float v = p[e];
#pragma unroll
            for (int off = 32; off >= 1; off >>= 1) v += __shfl_xor(v, off);
            p[e] = v;
        }
        if (lane == 0) {
            float mx = p[0];
#pragma unroll
            for (int e = 1; e < E_NUM; ++e) mx = fmaxf(mx, p[e]);
            float pe[E_NUM]; float s = 0.f;
#pragma unroll
            for (int e = 0; e < E_NUM; ++e) { pe[e] = expf(p[e] - mx); s += pe[e]; }
            const float inv = 1.f / s;
            int i0 = 0;
#pragma unroll
            for (int e = 1; e < E_NUM; ++e) if (pe[e] > pe[i0]) i0 = e;
            int i1 = -1;
#pragma unroll
            for (int e = 0; e < E_NUM; ++e) {
                if (e == i0) continue;
                if (i1 < 0 || pe[e] > pe[i1]) i1 = e;
            }
            const float p0 = pe[i0] * inv, p1 = pe[i1] * inv;
            const float wn = 1.f / (p0 + p1 + 1e-9f);
            topi[t * 2 + 0] = i0; topi[t * 2 + 1] = i1;
            topw[t * 2 + 0] = p0 * wn; topw[t * 2 + 1] = p1 * wn;
        }
    } else {
        // ------- weight conversion: grid-stride over 3 tensors of float4s
        const int W4 = E_NUM * H_DIM * D_DIM / 4;   // 4,194,304 per weight
        const int total = 3 * W4;
        const int stride = CONV_BLKS * 256;
        for (int i = (blockIdx.x - ROUTE_BLKS) * 256 + threadIdx.x; i < total;
             i += stride) {
            const float* s; unsigned short* d; int j;
            if (i < W4)          { s = wg; d = wgbf; j = i; }
            else if (i < 2 * W4) { s = wu; d = wubf; j = i - W4; }
            else                 { s = wd; d = wdbf; j = i - 2 * W4; }
            store4bf(d + (size_t)j * 4, ((const float4*)s)[j]);
        }
    }
}

// ---------------------------------------------------------------------------
// Router-only kernel (legacy fallback path)
// ---------------------------------------------------------------------------
__global__ __launch_bounds__(256) void router_k(
    const float* __restrict__ x, const float* __restrict__ gw,
    int* __restrict__ topi, float* __restrict__ topw,
    unsigned short* __restrict__ xbf) {
    const int t = blockIdx.x * 4 + (threadIdx.x >> 6);
    const int lane = threadIdx.x & 63;
    const float* xr = x + (size_t)t * D_DIM;
    unsigned short* xbr = xbf + (size_t)t * D_DIM;

    float p[E_NUM];
#pragma unroll
    for (int e = 0; e < E_NUM; ++e) p[e] = 0.f;
#pragma unroll
    for (int c = 0; c < 4; ++c) {
        const int idx = c * 256 + lane * 4;
        const float4 xv = *(const float4*)(xr + idx);
        store4bf(xbr + idx, xv);
#pragma unroll
        for (int e = 0; e < E_NUM; ++e) {
            const float4 gv = *(const float4*)(gw + e * D_DIM + idx);
            p[e] += xv.x * gv.x + xv.y * gv.y + xv.z * gv.z + xv.w * gv.w;
        }
    }
#pragma unroll
    for (int e = 0; e < E_NUM; ++e) {
        float v = p[e];
#pragma unroll
        for (int off = 32; off >= 1; off >>= 1) v += __shfl_xor(v, off);
        p[e] = v;
    }
    if (lane == 0) {
        float mx = p[0];
#pragma unroll
        for (int e = 1; e < E_NUM; ++e) mx = fmaxf(mx, p[e]);
        float pe[E_NUM]; float s = 0.f;
#pragma unroll
        for (int e = 0; e < E_NUM; ++e) { pe[e] = expf(p[e] - mx); s += pe[e]; }
        const float inv = 1.f / s;
        int i0 = 0;
#pragma unroll
        for (int e = 1; e < E_NUM; ++e) if (pe[e] > pe[i0]) i0 = e;
        int i1 = -1;
#pragma unroll
        for (int e = 0; e < E_NUM; ++e) {
            if (e == i0) continue;
            if (i1 < 0 || pe[e] > pe[i1]) i1 = e;
        }
        const float p0 = pe[i0] * inv, p1 = pe[i1] * inv;
        const float wn = 1.f / (p0 + p1 + 1e-9f);
        topi[t * 2 + 0] = i0; topi[t * 2 + 1] = i1;
        topw[t * 2 + 0] = p0 * wn; topw[t * 2 + 1] = p1 * wn;
    }
}

// ---------------------------------------------------------------------------
// Assignment: one block, 16 waves; wave (k,e) scans tokens in order.
// Layout: expert e slots = [k=0: e*CAP2 + 0..CAP) [k=1: e*CAP2+CAP ..).
// cnt[e*2+k] = kept count per (e,k). Pad slots: tok=0, w=0 (masked in down).
// ---------------------------------------------------------------------------
__global__ __launch_bounds__(1024) void assign_k(
    const int* __restrict__ topi, const float* __restrict__ topw,
    int* __restrict__ tok_list, float* __restrict__ w_list,
    int* __restrict__ cnt) {
    __shared__ unsigned char topiL[T_TOK * 2];   // 16 KB
    __shared__ int kept[2][E_NUM];
    const int tid = threadIdx.x;
    const int wid = tid >> 6, lane = tid & 63;
    const int k = wid >> 3, e = wid & 7;
    const uint64_t lt = (1ull << lane) - 1ull;

    for (int i = tid; i < T_TOK * 2 / 4; i += 1024) {
        const int4 v = ((const int4*)topi)[i];
        uchar4 b;
        b.x = (unsigned char)v.x; b.y = (unsigned char)v.y;
        b.z = (unsigned char)v.z; b.w = (unsigned char)v.w;
        ((uchar4*)topiL)[i] = b;
    }
    __syncthreads();

    // phase 1: total per-(k,e) counts
    int total = 0;
    for (int base = 0; base < T_TOK; base += 64) {
        const int idx = topiL[(base + lane) * 2 + k];
        total += __popcll(__ballot(idx == e));
    }
    if (lane == 0) {
        const int kc = min(total, CAP);
        kept[k][e] = kc;
        cnt[e * 2 + k] = kc;
    }
    __syncthreads();
    const int myBase = e * CAP2 + k * CAP;

    // phase 2: ordered compaction of kept tokens
    int running = 0, keptRun = 0;
    for (int base = 0; base < T_TOK; base += 64) {
        const int t = base + lane;
        const bool pred = (topiL[t * 2 + k] == e);
        const uint64_t m = __ballot(pred);
        const int rank = running + __popcll(m & lt);
        const bool keep = pred && (rank < CAP);
        const uint64_t km = __ballot(keep);
        if (keep) {
            const int slot = myBase + keptRun + __popcll(km & lt);
            tok_list[slot] = t;
            w_list[slot] = topw[t * 2 + k];
        }
        running += __popcll(m);
        keptRun += __popcll(km);
    }
    __syncthreads();
    // phase 3: pad unused slots (safe token 0, zero weight)
    for (int s = tid; s < E_NUM * CAP2; s += 1024) {
        const int ee = s / CAP2;
        const int rem = s - ee * CAP2;
        const int kk = rem / CAP, ls = rem - kk * CAP;
        if (ls >= kept[kk][ee]) { tok_list[s] = 0; w_list[s] = 0.f; }
    }
}

// ---------------------------------------------------------------------------
// Fused gate+up GEMM, bf16. BM=128, BN_GU=64 per matrix.
// BK=64 with XOR chunk swizzle: conflict-free ds_read_b128 (round-2/5
// verified: SQ_LDS_BANK_CONFLICT = 0). 32 KB LDS, 4 blocks/CU.
// NEW (r8): bijective XCD swizzle (m204). The 32 consecutive x-blocks
// sharing one A-panel were round-robined across all 8 XCDs -> each per-XCD
// L2 fetched its own copy (gateup FETCH 180 MB vs ~97 ideal). Swizzle
// s = (j%8)*(nwg/8) + j/8 places each panel-sharing group on ONE XCD.
// nwg = 640*ne, always divisible by 8 -> bijective.
// ---------------------------------------------------------------------------
__global__ __launch_bounds__(256, 4) void gateup_bf_k(
    const unsigned short* __restrict__ xbf,
    const unsigned short* __restrict__ wgbf, const unsigned short* __restrict__ wubf,
    const int* __restrict__ tok_list, const int* __restrict__ cnt,
    unsigned short* __restrict__ h_ws, int e0) {
    // ---- XCD swizzle: remap dispatch-order id j -> work id s ----
    const int nwg = 640 * gridDim.z;                 // 32 * 20 * ne
    const int j = blockIdx.x + (blockIdx.y << 5) + blockIdx.z * 640;
    const int s = (j & 7) * (nwg >> 3) + (j >> 3);
    const int bx = s & 31;                           // n-tile (32)
    const int t2 = s >> 5;
    const int by = t2 % 20;                          // m-tile/region (20)
    const int ez = t2 / 20;                          // expert (ne)

    const int e = e0 + ez;
    const int kk = by / MT_K;
    const int m0 = (by - kk * MT_K) * BM;
    if (m0 >= cnt[e * 2 + kk]) return;
    const int n0 = bx * BN_GU;
    const int sbase = e * CAP2 + kk * CAP + m0;           // global slot base
    const size_t hbase = (size_t)ez * CAP2 + kk * CAP + m0;

    // A: 128x64 (16 KB) | Bg: 64x64 (8 KB) | Bu: 64x64 (8 KB) = 32 KB
    __shared__ __align__(1024) unsigned short smem[16384];

    const int tid = threadIdx.x, wid = tid >> 6, lane = tid & 63;

    const unsigned short* gsrc[8];
    int ldsoff[8];
#pragma unroll
    for (int i = 0; i < 8; ++i) {
        const int f = (wid * 8 + i) * 64 + lane;   // 16B slot index, 0..2047
        const unsigned short* g;
        if (f < 1024) {                  // A: 128 rows x 8 chunks, swizzled
            const int r = f >> 3, c = (f & 7) ^ (r & 7);
            const int tok = tok_list[sbase + r];
            g = xbf + (size_t)tok * D_DIM + c * 8;
        } else if (f < 1536) {           // Bg: 64 rows x 8 chunks, swizzled
            const int fr = f - 1024;
            const int r = fr >> 3, c = (fr & 7) ^ (r & 7);
            g = wgbf + ((size_t)e * H_DIM + n0 + r) * D_DIM + c * 8;
        } else {                         // Bu: 64 rows x 8 chunks, swizzled
            const int fr = f - 1536;
            const int r = fr >> 3, c = (fr & 7) ^ (r & 7);
            g = wubf + ((size_t)e * H_DIM + n0 + r) * D_DIM + c * 8;
        }
        gsrc[i] = g;
        ldsoff[i] = (wid * 8 + i) * 1024;   // bytes, wave-uniform
    }

    float4v accg[4][2], accu[4][2];
#pragma unroll
    for (int i = 0; i < 4; ++i)
#pragma unroll
        for (int jj = 0; jj < 2; ++jj) {
            accg[i][jj] = (float4v){0.f, 0.f, 0.f, 0.f};
            accu[i][jj] = (float4v){0.f, 0.f, 0.f, 0.f};
        }

    const int wm = (wid & 1) * 64;       // wave M-offset: 2 waves over 128 rows
    const int wn = (wid >> 1) * 32;      // wave N-offset: 2 waves over 64 cols
    const int frow = lane & 15;
    const int quad = lane >> 4;

    for (int k0 = 0; k0 < D_DIM; k0 += 64) {
#pragma unroll
        for (int i = 0; i < 8; ++i)
            __builtin_amdgcn_global_load_lds(
                (gu32*)(gsrc[i] + k0),
                (lu32*)((char*)smem + ldsoff[i]), 16, 0, 0);
        __syncthreads();

#pragma unroll
        for (int sp = 0; sp < 2; ++sp) {
            const int c = sp * 4 + quad;          // chunk: k = sp*32 + quad*8
            short8 af[4], bgf[2], buf[2];
#pragma unroll
            for (int i = 0; i < 4; ++i) {
                const int row = wm + i * 16 + frow;
                af[i] = *(const short8*)&smem[(row * 8 + (c ^ (row & 7))) * 8];
            }
#pragma unroll
            for (int jj = 0; jj < 2; ++jj) {
                const int row = wn + jj * 16 + frow;
                bgf[jj] = *(const short8*)&smem[8192 + (row * 8 + (c ^ (row & 7))) * 8];
                buf[jj] = *(const short8*)&smem[12288 + (row * 8 + (c ^ (row & 7))) * 8];
            }
#pragma unroll
            for (int i = 0; i < 4; ++i)
#pragma unroll
                for (int jj = 0; jj < 2; ++jj) {
                    accg[i][jj] = __builtin_amdgcn_mfma_f32_16x16x32_bf16(af[i], bgf[jj], accg[i][jj], 0, 0, 0);
                    accu[i][jj] = __builtin_amdgcn_mfma_f32_16x16x32_bf16(af[i], buf[jj], accu[i][jj], 0, 0, 0);
                }
        }
        __syncthreads();
    }

    const int col = lane & 15, rbase = (lane >> 4) * 4;
#pragma unroll
    for (int i = 0; i < 4; ++i)
#pragma unroll
        for (int jj = 0; jj < 2; ++jj)
#pragma unroll
            for (int r = 0; r < 4; ++r) {
                const float g = accg[i][jj][r];
                const float u = accu[i][jj][r];
                const float hv = (g / (1.f + __expf(-g))) * u;
                const int m = wm + i * 16 + rbase + r;
                const int n = wn + jj * 16 + col;
                h_ws[(hbase + m) * H_DIM + (n0 + n)] = f2bf(hv);
            }
}

// ---------------------------------------------------------------------------
// Down GEMM, SPLIT-BUFFER merged form. REVERTED to 3 blocks/CU (r7's
// bounds-4 regressed: FETCH 450 MB, dur 213 µs — cache thrash, not fill).
// NEW (r8): bijective XCD swizzle (m204). Diagnosis from r7 counters:
// FETCH 450 MB vs ~118 ideal because the 8 consecutive x-blocks sharing an
// A-panel (h rows) round-robin across all 8 XCDs -> 8x duplicated L2 fills
// (84 MB x 8 = 672 upper bound). Swizzle groups them on one XCD; each XCD
// then owns 2 whole (e,kk) regions (z-slab = 80 ids, chunk = 160).
// kk=0 -> out, kk=1 -> out2 (both pre-zeroed), no atomics; combine_k adds.
// ---------------------------------------------------------------------------
__global__ __launch_bounds__(256, 3) void down_split_bf_k(
    const unsigned short* __restrict__ h_ws, const unsigned short* __restrict__ wdbf,
    const int* __restrict__ tok_list, const float* __restrict__ w_list,
    const int* __restrict__ cnt, float* __restrict__ out,
    float* __restrict__ out2, int e0) {
    // ---- XCD swizzle: remap dispatch-order id j -> work id s ----
    const int nwg = 80 * gridDim.z;                  // 8 * 10 * 2ne
    const int j = blockIdx.x + (blockIdx.y << 3) + blockIdx.z * 80;
    const int s = (j & 7) * (nwg >> 3) + (j >> 3);
    const int bx = s & 7;                            // n-tile (8)
    const int t2 = s >> 3;
    const int by = t2 % 10;                          // m-tile (10)
    const int zz = t2 / 10;                          // region (2ne)

    const int ez = zz >> 1;
    const int kk = zz & 1;
    const int e = e0 + ez;
    const int m0 = by * BM;
    const int nkept = cnt[e * 2 + kk];
    if (m0 >= nkept) return;
    const int n0 = bx * BN;
    const int sbase = e * CAP2 + kk * CAP + m0;
    const size_t hbase = (size_t)ez * CAP2 + kk * CAP + m0;

    __shared__ __align__(1024) unsigned short smem[16384];   // 32 KB: A|B
    __shared__ int tokL[BM];
    __shared__ float wL[BM];

    const int tid = threadIdx.x, wid = tid >> 6, lane = tid & 63;
    if (tid < BM) {
        tokL[tid] = tok_list[sbase + tid];
        wL[tid] = w_list[sbase + tid];
    }

    const unsigned short* gsrc[8];
    int ldsoff[8];
#pragma unroll
    for (int i = 0; i < 8; ++i) {
        const int f = (wid * 8 + i) * 64 + lane;   // 16B slot index, 0..2047
        const unsigned short* g;
        if (f < 1024) {          // A region: h rows, 128 rows x 8 chunks
            const int r = f >> 3, c = (f & 7) ^ (r & 7);
            g = h_ws + (hbase + r) * H_DIM + c * 8;
        } else {                 // B region: wd rows
            const int fr = f - 1024;
            const int r = fr >> 3, c = (fr & 7) ^ (r & 7);
            g = wdbf + ((size_t)e * D_DIM + n0 + r) * H_DIM + c * 8;
        }
        gsrc[i] = g;
        ldsoff[i] = (wid * 8 + i) * 1024;   // bytes, wave-uniform
    }

    float4v acc[4][4];
#pragma unroll
    for (int i = 0; i < 4; ++i)
#pragma unroll
        for (int jj = 0; jj < 4; ++jj) acc[i][jj] = (float4v){0.f, 0.f, 0.f, 0.f};

    const int wm = (wid & 1) * 64, wn = (wid >> 1) * 64;
    const int frow = lane & 15;
    const int quad = lane >> 4;

    for (int k0 = 0; k0 < H_DIM; k0 += 64) {
#pragma unroll
        for (int i = 0; i < 8; ++i)
            __builtin_amdgcn_global_load_lds(
                (gu32*)(gsrc[i] + k0),
                (lu32*)((char*)smem + ldsoff[i]), 16, 0, 0);
        __syncthreads();

#pragma unroll
        for (int sp = 0; sp < 2; ++sp) {
            const int c = sp * 4 + quad;
            short8 af[4], bf[4];
#pragma unroll
            for (int i = 0; i < 4; ++i) {
                const int row = wm + i * 16 + frow;
                af[i] = *(const short8*)&smem[(row * 8 + (c ^ (row & 7))) * 8];
            }
#pragma unroll
            for (int jj = 0; jj < 4; ++jj) {
                const int row = wn + jj * 16 + frow;
                bf[jj] = *(const short8*)&smem[8192 + (row * 8 + (c ^ (row & 7))) * 8];
            }
#pragma unroll
            for (int i = 0; i < 4; ++i)
#pragma unroll
                for (int jj = 0; jj < 4; ++jj)
                    acc[i][jj] = __builtin_amdgcn_mfma_f32_16x16x32_bf16(af[i], bf[jj], acc[i][jj], 0, 0, 0);
        }
        __syncthreads();
    }

    // Epilogue: plain stores to the kk-selected buffer; pad rows masked.
    float* dbuf = kk ? out2 : out;
    const int col = lane & 15, rbase = (lane >> 4) * 4;
#pragma unroll
    for (int i = 0; i < 4; ++i)
#pragma unroll
        for (int r = 0; r < 4; ++r) {
            const int m = wm + i * 16 + rbase + r;
            if (m0 + m >= nkept) continue;       // pad row: skip
            const float wRow = wL[m];
            float* orow = dbuf + (size_t)tokL[m] * D_DIM + n0;
#pragma unroll
            for (int jj = 0; jj < 4; ++jj) {
                const int n = jj * 16 + wn + col;
                orow[n] = acc[i][jj][r] * wRow;
            }
        }
}

// combine: out += out2 (float4 grid-stride, ~100 MB traffic)
__global__ __launch_bounds__(256) void combine_k(
    float* __restrict__ out, const float* __restrict__ out2) {
    const int total = T_TOK * D_DIM / 4;   // 2,097,152 float4s
    const int stride = gridDim.x * 256;
    for (int i = blockIdx.x * 256 + threadIdx.x; i < total; i += stride) {
        float4 a = ((float4*)out)[i];
        const float4 b = ((const float4*)out2)[i];
        a.x += b.x; a.y += b.y; a.z += b.z; a.w += b.w;
        ((float4*)out)[i] = a;
    }
}

// ---------------------------------------------------------------------------
// Down GEMM two-pass form (round-5 verified fallback when out2 doesn't fit).
// Pass kk=0: plain stores. Pass kk=1: load-add-store. Pad rows masked.
// ---------------------------------------------------------------------------
__global__ __launch_bounds__(256, 3) void down_bf_k(
    const unsigned short* __restrict__ h_ws, const unsigned short* __restrict__ wdbf,
    const int* __restrict__ tok_list, const float* __restrict__ w_list,
    const int* __restrict__ cnt, float* __restrict__ out, int e0, int kk) {
    const int ez = blockIdx.z;
    const int e = e0 + ez;
    const int m0 = blockIdx.y * BM;
    const int nkept = cnt[e * 2 + kk];
    if (m0 >= nkept) return;
    const int n0 = blockIdx.x * BN;
    const int sbase = e * CAP2 + kk * CAP + m0;
    const size_t hbase = (size_t)ez * CAP2 + kk * CAP + m0;

    __shared__ __align__(1024) unsigned short smem[16384];   // 32 KB: A|B
    __shared__ int tokL[BM];
    __shared__ float wL[BM];

    const int tid = threadIdx.x, wid = tid >> 6, lane = tid & 63;
    if (tid < BM) {
        tokL[tid] = tok_list[sbase + tid];
        wL[tid] = w_list[sbase + tid];
    }

    const unsigned short* gsrc[8];
    int ldsoff[8];
#pragma unroll
    for (int i = 0; i < 8; ++i) {
        const int f = (wid * 8 + i) * 64 + lane;   // 16B slot index, 0..2047
        const unsigned short* g;
        if (f < 1024) {          // A region: h rows, 128 rows x 8 chunks
            const int r = f >> 3, c = (f & 7) ^ (r & 7);
            g = h_ws + (hbase + r) * H_DIM + c * 8;
        } else {                 // B region: wd rows
            const int fr = f - 1024;
            const int r = fr >> 3, c = (fr & 7) ^ (r & 7);
            g = wdbf + ((size_t)e * D_DIM + n0 + r) * H_DIM + c * 8;
        }
        gsrc[i] = g;
        ldsoff[i] = (wid * 8 + i) * 1024;   // bytes, wave-uniform
    }

    float4v acc[4][4];
#pragma unroll
    for (int i = 0; i < 4; ++i)
#pragma unroll
        for (int j = 0; j < 4; ++j) acc[i][j] = (float4v){0.f, 0.f, 0.f, 0.f};

    const int wm = (wid & 1) * 64, wn = (wid >> 1) * 64;
    const int frow = lane & 15;
    const int quad = lane >> 4;

    for (int k0 = 0; k0 < H_DIM; k0 += 64) {
#pragma unroll
        for (int i = 0; i < 8; ++i)
            __builtin_amdgcn_global_load_lds(
                (gu32*)(gsrc[i] + k0),
                (lu32*)((char*)smem + ldsoff[i]), 16, 0, 0);
        __syncthreads();

#pragma unroll
        for (int s = 0; s < 2; ++s) {
            const int c = s * 4 + quad;
            short8 af[4], bf[4];
#pragma unroll
            for (int i = 0; i < 4; ++i) {
                const int row = wm + i * 16 + frow;
                af[i] = *(const short8*)&smem[(row * 8 + (c ^ (row & 7))) * 8];
            }
#pragma unroll
            for (int j = 0; j < 4; ++j) {
                const int row = wn + j * 16 + frow;
                bf[j] = *(const short8*)&smem[8192 + (row * 8 + (c ^ (row & 7))) * 8];
            }
#pragma unroll
            for (int i = 0; i < 4; ++i)
#pragma unroll
                for (int j = 0; j < 4; ++j)
                    acc[i][j] = __builtin_amdgcn_mfma_f32_16x16x32_bf16(af[i], bf[j], acc[i][j], 0, 0, 0);
        }
        __syncthreads();
    }

    // Epilogue: plain store (kk=0) or load-add-store (kk=1); pad rows masked.
    const int col = lane & 15, rbase = (lane >> 4) * 4;
#pragma unroll
    for (int i = 0; i < 4; ++i)
#pragma unroll
        for (int r = 0; r < 4; ++r) {
            const int m = wm + i * 16 + rbase + r;
            if (m0 + m >= nkept) continue;       // pad row: skip (avoid races)
            const float wRow = wL[m];
            float* orow = out + (size_t)tokL[m] * D_DIM + n0;
#pragma unroll
            for (int j = 0; j < 4; ++j) {
                const int n = j * 16 + wn + col;
                const float v = acc[i][j][r] * wRow;
                if (kk == 0) orow[n] = v;
                else         orow[n] += v;
            }
        }
}

// ---------------------------------------------------------------------------
// Legacy fp32-staging kernels (fallback if workspace too small for bf16 path)
// ---------------------------------------------------------------------------
__global__ __launch_bounds__(256, 2) void gateup_legacy_k(
    const float* __restrict__ x,
    const float* __restrict__ wg_all, const float* __restrict__ wu_all,
    const int* __restrict__ tok_list, const int* __restrict__ cnt,
    unsigned short* __restrict__ h_ws, int e0) {
    const int ez = blockIdx.z;
    const int e = e0 + ez;
    const int kk = blockIdx.y / MT_K;
    const int m0 = (blockIdx.y - kk * MT_K) * BM;
    if (m0 >= cnt[e * 2 + kk]) return;
    const int n0 = blockIdx.x * BN;
    const int sbase = e * CAP2 + kk * CAP + m0;
    const size_t hbase = (size_t)ez * CAP2 + kk * CAP + m0;

    __shared__ __align__(16) unsigned short As[BM][BK];
    __shared__ __align__(16) unsigned short Bg[BN][BK];
    __shared__ __align__(16) unsigned short Bu[BN][BK];
    __shared__ int tokL[BM];

    const int tid = threadIdx.x;
    if (tid < BM) tokL[tid] = tok_list[sbase + tid];
    __syncthreads();

    const float* wg = wg_all + (size_t)e * H_DIM * D_DIM;
    const float* wu = wu_all + (size_t)e * H_DIM * D_DIM;

    const float* aSrc[4]; const float* gSrc[4]; const float* uSrc[4];
    unsigned short* aDst[4]; unsigned short* gDst[4]; unsigned short* uDst[4];
#pragma unroll
    for (int it = 0; it < 4; ++it) {
        const int fid = it * 256 + tid;
        const int row = fid >> 3;
        const int c4 = (fid & 7) * 4;
        aSrc[it] = x + (size_t)tokL[row] * D_DIM + c4;
        gSrc[it] = wg + (size_t)(n0 + row) * D_DIM + c4;
        uSrc[it] = wu + (size_t)(n0 + row) * D_DIM + c4;
        aDst[it] = &As[row][c4];
        gDst[it] = &Bg[row][c4];
        uDst[it] = &Bu[row][c4];
    }

    float4v accg[4][4], accu[4][4];
#pragma unroll
    for (int i = 0; i < 4; ++i)
#pragma unroll
        for (int j = 0; j < 4; ++j) {
            accg[i][j] = (float4v){0.f, 0.f, 0.f, 0.f};
            accu[i][j] = (float4v){0.f, 0.f, 0.f, 0.f};
        }

    const int wid = tid >> 6, lane = tid & 63;
    const int wm = (wid & 1) * 64, wn = (wid >> 1) * 64;
    const int frow = lane & 15;
    const int fk = (lane >> 4) * 8;

    for (int k0 = 0; k0 < D_DIM; k0 += BK) {
#pragma unroll
        for (int it = 0; it < 4; ++it) {
            store4bf(aDst[it], *(const float4*)(aSrc[it] + k0));
            store4bf(gDst[it], *(const float4*)(gSrc[it] + k0));
            store4bf(uDst[it], *(const float4*)(uSrc[it] + k0));
        }
        __syncthreads();
        short8 af[4], bgf[4], buf[4];
#pragma unroll
        for (int i = 0; i < 4; ++i)
            af[i] = *(const short8*)&As[wm + i * 16 + frow][fk];
#pragma unroll
        for (int j = 0; j < 4; ++j) {
            bgf[j] = *(const short8*)&Bg[wn + j * 16 + frow][fk];
            buf[j] = *(const short8*)&Bu[wn + j * 16 + frow][fk];
        }
#pragma unroll
        for (int i = 0; i < 4; ++i)
#pragma unroll
            for (int j = 0; j < 4; ++j) {
                accg[i][j] = __builtin_amdgcn_mfma_f32_16x16x32_bf16(af[i], bgf[j], accg[i][j], 0, 0, 0);
                accu[i][j] = __builtin_amdgcn_mfma_f32_16x16x32_bf16(af[i], buf[j], accu[i][j], 0, 0, 0);
            }
        __syncthreads();
    }

    const int col = lane & 15, rbase = (lane >> 4) * 4;
#pragma unroll
    for (int i = 0; i < 4; ++i)
#pragma unroll
        for (int j = 0; j < 4; ++j)
#pragma unroll
            for (int r = 0; r < 4; ++r) {
                const float g = accg[i][j][r];
                const float u = accu[i][j][r];
                const float hv = (g / (1.f + __expf(-g))) * u;
                const int m = wm + i * 16 + rbase + r;
                const int n = wn + j * 16 + col;
                h_ws[(hbase + m) * H_DIM + (n0 + n)] = f2bf(hv);
            }
}

__global__ __launch_bounds__(256, 2) void down_legacy_k(
    const unsigned short* __restrict__ h_ws, const float* __restrict__ wd_all,
    const int* __restrict__ tok_list, const float* __restrict__ w_list,
    const int* __restrict__ cnt, float* __restrict__ out, int e0) {
    const int ez = blockIdx.z;
    const int e = e0 + ez;
    const int kk = blockIdx.y / MT_K;
    const int m0 = (blockIdx.y - kk * MT_K) * BM;
    if (m0 >= cnt[e * 2 + kk]) return;
    const int n0 = blockIdx.x * BN;
    const int sbase = e * CAP2 + kk * CAP + m0;
    const size_t hbase = (size_t)ez * CAP2 + kk * CAP + m0;

    __shared__ __align__(16) unsigned short As[BM][BK];
    __shared__ __align__(16) unsigned short Bs[BN][BK];
    __shared__ int tokL[BM];
    __shared__ float wL[BM];

    const int tid = threadIdx.x;
    if (tid < BM) {
        tokL[tid] = tok_list[sbase + tid];
        wL[tid] = w_list[sbase + tid];
    }
    __syncthreads();

    const unsigned short* hA = h_ws + hbase * H_DIM;
    const float* wd = wd_all + (size_t)e * D_DIM * H_DIM;

    const unsigned short* aSrc[2]; unsigned short* aDst[2];
#pragma unroll
    for (int it = 0; it < 2; ++it) {
        const int fid = it * 256 + tid;
        const int row = fid >> 2;
        const int c8 = (fid & 3) * 8;
        aSrc[it] = hA + (size_t)row * H_DIM + c8;
        aDst[it] = &As[row][c8];
    }
    const float* bSrc[4]; unsigned short* bDst[4];
#pragma unroll
    for (int it = 0; it < 4; ++it) {
        const int fid = it * 256 + tid;
        const int row = fid >> 3;
        const int c4 = (fid & 7) * 4;
        bSrc[it] = wd + (size_t)(n0 + row) * H_DIM + c4;
        bDst[it] = &Bs[row][c4];
    }

    float4v acc[4][4];
#pragma unroll
    for (int i = 0; i < 4; ++i)
#pragma unroll
        for (int j = 0; j < 4; ++j) acc[i][j] = (float4v){0.f, 0.f, 0.f, 0.f};

    const int wid = tid >> 6, lane = tid & 63;
    const int wm = (wid & 1) * 64, wn = (wid >> 1) * 64;
    const int frow = lane & 15;
    const int fk = (lane >> 4) * 8;

    for (int k0 = 0; k0 < H_DIM; k0 += BK) {
#pragma unroll
        for (int it = 0; it < 2; ++it)
            *(uint4*)aDst[it] = *(const uint4*)(aSrc[it] + k0);
#pragma unroll
        for (int it = 0; it < 4; ++it)
            store4bf(bDst[it], *(const float4*)(bSrc[it] + k0));
        __syncthreads();
        short8 af[4], bf[4];
#pragma unroll
        for (int i = 0; i < 4; ++i)
            af[i] = *(const short8*)&As[wm + i * 16 + frow][fk];
#pragma unroll
        for (int j = 0; j < 4; ++j)
            bf[j] = *(const short8*)&Bs[wn + j * 16 + frow][fk];
#pragma unroll
        for (int i = 0; i < 4; ++i)
#pragma unroll
            for (int j = 0; j < 4; ++j)
                acc[i][j] = __builtin_amdgcn_mfma_f32_16x16x32_bf16(af[i], bf[j], acc[i][j], 0, 0, 0);
        __syncthreads();
    }

    const int col = lane & 15, rbase = (lane >> 4) * 4;
#pragma unroll
    for (int i = 0; i < 4; ++i)
#pragma unroll
        for (int j = 0; j < 4; ++j)
#pragma unroll
            for (int r = 0; r < 4; ++r) {
                const int m = wm + i * 16 + rbase + r;
                const int n = wn + j * 16 + col;
                const float v = acc[i][j][r] * wL[m];
                unsafeAtomicAdd(&out[(size_t)tokL[m] * D_DIM + n0 + n], v);
            }
}

// ---------------------------------------------------------------------------
extern "C" void kernel_launch(void* const* d_in, const int* in_sizes, int n_in,
                              void* d_out, int out_size, void* d_ws, size_t ws_size,
                              hipStream_t stream) {
    const float* x        = (const float*)d_in[0];
    const float* gate_w   = (const float*)d_in[1];
    const float* gate_pw  = (const float*)d_in[2];
    const float* up_pw    = (const float*)d_in[3];
    const float* down_pw  = (const float*)d_in[4];
    float* out = (float*)d_out;
    (void)n_in; (void)in_sizes; (void)out_size;

    uint8_t* ws = (uint8_t*)d_ws;
    size_t off = 0;
    int*   topi     = (int*)(ws + off);   off += (size_t)T_TOK * 2 * 4;
    float* topw     = (float*)(ws + off); off += (size_t)T_TOK * 2 * 4;
    int*   tok_list = (int*)(ws + off);   off += (size_t)E_NUM * CAP2 * 4;
    float* w_list   = (float*)(ws + off); off += (size_t)E_NUM * CAP2 * 4;
    int*   cnt      = (int*)(ws + off);   off += 256;
    off = (off + 4095) & ~(size_t)4095;
    const size_t routing_end = off;

    const size_t x_elems = (size_t)T_TOK * D_DIM;           // 8.4 M
    const size_t w_elems = (size_t)E_NUM * H_DIM * D_DIM;   // 16.8 M each
    unsigned short* xbf  = (unsigned short*)(ws + off); off += x_elems * 2;
    unsigned short* wgbf = (unsigned short*)(ws + off); off += w_elems * 2;
    unsigned short* wubf = (unsigned short*)(ws + off); off += w_elems * 2;
    unsigned short* wdbf = (unsigned short*)(ws + off); off += w_elems * 2;
    const size_t need_base = off;                           // ~118 MB
    const size_t out2_sz = (size_t)T_TOK * D_DIM * 4;       // 33.5 MB
    const size_t per_e = (size_t)CAP2 * H_DIM * 2;          // 10.5 MB / expert

    hipMemsetAsync(out, 0, (size_t)T_TOK * D_DIM * sizeof(float), stream);

    if (ws_size >= need_base + out2_sz + per_e) {
        // bf16 fast path with split-buffer merged down
        float* out2 = (float*)(ws + need_base);
        unsigned short* h_ws = (unsigned short*)(ws + need_base + out2_sz);
        int chunk = (int)((ws_size - need_base - out2_sz) / per_e);
        if (chunk > E_NUM) chunk = E_NUM;

        hipMemsetAsync(out2, 0, out2_sz, stream);
        prep_k<<<ROUTE_BLKS + CONV_BLKS, 256, 0, stream>>>(
            x, gate_w, topi, topw, xbf,
            gate_pw, up_pw, down_pw, wgbf, wubf, wdbf);
        assign_k<<<1, 1024, 0, stream>>>(topi, topw, tok_list, w_list, cnt);

        for (int e0 = 0; e0 < E_NUM; e0 += chunk) {
            const int ne = (e0 + chunk <= E_NUM) ? chunk : (E_NUM - e0);
            dim3 g1(H_DIM / BN_GU, 2 * MT_K, ne);
            gateup_bf_k<<<g1, 256, 0, stream>>>(xbf, wgbf, wubf, tok_list, cnt, h_ws, e0);
            dim3 g2(D_DIM / BN, MT_K, 2 * ne);
            down_split_bf_k<<<g2, 256, 0, stream>>>(h_ws, wdbf, tok_list, w_list,
                                                    cnt, out, out2, e0);
        }
        combine_k<<<2048, 256, 0, stream>>>(out, out2);
    } else if (ws_size >= need_base + per_e) {
        // bf16 path, two-pass down (round-5 verified) when out2 doesn't fit
        unsigned short* h_ws = (unsigned short*)(ws + need_base);
        int chunk = (int)((ws_size - need_base) / per_e);
        if (chunk > E_NUM) chunk = E_NUM;

        prep_k<<<ROUTE_BLKS + CONV_BLKS, 256, 0, stream>>>(
            x, gate_w, topi, topw, xbf,
            gate_pw, up_pw, down_pw, wgbf, wubf, wdbf);
        assign_k<<<1, 1024, 0, stream>>>(topi, topw, tok_list, w_list, cnt);

        for (int e0 = 0; e0 < E_NUM; e0 += chunk) {
            const int ne = (e0 + chunk <= E_NUM) ? chunk : (E_NUM - e0);
            dim3 g1(H_DIM / BN_GU, 2 * MT_K, ne);
            gateup_bf_k<<<g1, 256, 0, stream>>>(xbf, wgbf, wubf, tok_list, cnt, h_ws, e0);
            dim3 g2(D_DIM / BN, MT_K, ne);
            down_bf_k<<<g2, 256, 0, stream>>>(h_ws, wdbf, tok_list, w_list, cnt, out, e0, 0);
            down_bf_k<<<g2, 256, 0, stream>>>(h_ws, wdbf, tok_list, w_list, cnt, out, e0, 1);
        }
    } else {
        // legacy fp32-staging path (small workspace)
        unsigned short* h_ws = (unsigned short*)(ws + routing_end);
        int chunk = (ws_size > routing_end) ? (int)((ws_size - routing_end) / per_e) : 0;
        if (chunk > E_NUM) chunk = E_NUM;
        if (chunk < 1) chunk = 1;

        router_k<<<T_TOK / 4, 256, 0, stream>>>(x, gate_w, topi, topw, xbf);
        assign_k<<<1, 1024, 0, stream>>>(topi, topw, tok_list, w_list, cnt);

        for (int e0 = 0; e0 < E_NUM; e0 += chunk) {
            const int ne = (e0 + chunk <= E_NUM) ? chunk : (E_NUM - e0);
            dim3 g1(H_DIM / BN, 2 * MT_K, ne);
            gateup_legacy_k<<<g1, 256, 0, stream>>>(x, gate_pw, up_pw, tok_list, cnt, h_ws, e0);
            dim3 g2(D_DIM / BN, 2 * MT_K, ne);
            down_legacy_k<<<g2, 256, 0, stream>>>(h_ws, down_pw, tok_list, w_list, cnt, out, e0);
        }
    }
}

// Round 9
// 587.439 us; speedup vs baseline: 1.1886x; 1.0061x over previous
//
#include <hip/hip_runtime.h>
#include <hip/hip_bf16.h>
#include <stdint.h>

// Problem constants (fixed by setup_inputs)
#define T_TOK 8192
#define D_DIM 1024
#define H_DIM 2048
#define E_NUM 8
#define CAP   1280       // int(1.25 * T / E)
#define CAP2  2560       // per expert: [k=0: CAP slots][k=1: CAP slots]
#define MT_K  10         // M-tiles per (e,k) region: CAP/BM

#define BM 128
#define BN 128
#define BN_GU 64         // gateup N-tile per matrix (acc = 64 f32/thread)
#define BK 32

#define ROUTE_BLKS (T_TOK / 4)   // 2048 router blocks in prep_k
#define CONV_BLKS  4096          // conversion blocks in prep_k

typedef __attribute__((ext_vector_type(8))) short short8;   // 8 bf16 (4 VGPRs)
typedef __attribute__((ext_vector_type(4))) float float4v;  // MFMA C/D
typedef __attribute__((address_space(1))) const unsigned int gu32;
typedef __attribute__((address_space(3))) unsigned int lu32;

static __device__ __forceinline__ unsigned short f2bf(float f) {
    unsigned int u = __float_as_uint(f);
    unsigned int r = (u + 0x7FFFu + ((u >> 16) & 1u)) >> 16;  // RNE
    return (unsigned short)r;
}

static __device__ __forceinline__ void store4bf(unsigned short* d, float4 v) {
    union { unsigned short u[4]; uint2 q; } pk;
    pk.u[0] = f2bf(v.x); pk.u[1] = f2bf(v.y);
    pk.u[2] = f2bf(v.z); pk.u[3] = f2bf(v.w);
    *(uint2*)d = pk.q;
}

// ---------------------------------------------------------------------------
// prep_k: router (blocks 0..ROUTE_BLKS) and fp32->bf16 weight conversion
// (remaining CONV_BLKS) merged into ONE dispatch so the two independent
// pieces overlap instead of serializing on the stream.
// ---------------------------------------------------------------------------
__global__ __launch_bounds__(256) void prep_k(
    const float* __restrict__ x, const float* __restrict__ gw,
    int* __restrict__ topi, float* __restrict__ topw,
    unsigned short* __restrict__ xbf,
    const float* __restrict__ wg, const float* __restrict__ wu,
    const float* __restrict__ wd,
    unsigned short* __restrict__ wgbf, unsigned short* __restrict__ wubf,
    unsigned short* __restrict__ wdbf) {
    if (blockIdx.x < ROUTE_BLKS) {
        // ------- router: 4 waves/block, one wave per token; converts x->bf16
        const int t = blockIdx.x * 4 + (threadIdx.x >> 6);
        const int lane = threadIdx.x & 63;
        const float* xr = x + (size_t)t * D_DIM;
        unsigned short* xbr = xbf + (size_t)t * D_DIM;

        float p[E_NUM];
#pragma unroll
        for (int e = 0; e < E_NUM; ++e) p[e] = 0.f;
#pragma unroll
        for (int c = 0; c < 4; ++c) {
            const int idx = c * 256 + lane * 4;
            const float4 xv = *(const float4*)(xr + idx);
            store4bf(xbr + idx, xv);
#pragma unroll
            for (int e = 0; e < E_NUM; ++e) {
                const float4 gv = *(const float4*)(gw + e * D_DIM + idx);
                p[e] += xv.x * gv.x + xv.y * gv.y + xv.z * gv.z + xv.w * gv.w;
            }
        }
#pragma unroll
        for (int e = 0; e < E_NUM; ++e) {
            float v = p[e];
#pragma unroll
            for (int off = 32; off >= 1; off >>= 1) v += __shfl_xor(v, off);
            p[e] = v;
        }
        if (lane == 0) {
            float mx = p[0];
#pragma unroll
            for (int e = 1; e < E_NUM; ++e) mx = fmaxf(mx, p[e]);
            float pe[E_NUM]; float s = 0.f;
#pragma unroll
            for (int e = 0; e < E_NUM; ++e) { pe[e] = expf(p[e] - mx); s += pe[e]; }
            const float inv = 1.f / s;
            int i0 = 0;
#pragma unroll
            for (int e = 1; e < E_NUM; ++e) if (pe[e] > pe[i0]) i0 = e;
            int i1 = -1;
#pragma unroll
            for (int e = 0; e < E_NUM; ++e) {
                if (e == i0) continue;
                if (i1 < 0 || pe[e] > pe[i1]) i1 = e;
            }
            const float p0 = pe[i0] * inv, p1 = pe[i1] * inv;
            const float wn = 1.f / (p0 + p1 + 1e-9f);
            topi[t * 2 + 0] = i0; topi[t * 2 + 1] = i1;
            topw[t * 2 + 0] = p0 * wn; topw[t * 2 + 1] = p1 * wn;
        }
    } else {
        // ------- weight conversion: grid-stride over 3 tensors of float4s
        const int W4 = E_NUM * H_DIM * D_DIM / 4;   // 4,194,304 per weight
        const int total = 3 * W4;
        const int stride = CONV_BLKS * 256;
        for (int i = (blockIdx.x - ROUTE_BLKS) * 256 + threadIdx.x; i < total;
             i += stride) {
            const float* s; unsigned short* d; int j;
            if (i < W4)          { s = wg; d = wgbf; j = i; }
            else if (i < 2 * W4) { s = wu; d = wubf; j = i - W4; }
            else                 { s = wd; d = wdbf; j = i - 2 * W4; }
            store4bf(d + (size_t)j * 4, ((const float4*)s)[j]);
        }
    }
}

// ---------------------------------------------------------------------------
// Router-only kernel (legacy fallback path)
// ---------------------------------------------------------------------------
__global__ __launch_bounds__(256) void router_k(
    const float* __restrict__ x, const float* __restrict__ gw,
    int* __restrict__ topi, float* __restrict__ topw,
    unsigned short* __restrict__ xbf) {
    const int t = blockIdx.x * 4 + (threadIdx.x >> 6);
    const int lane = threadIdx.x & 63;
    const float* xr = x + (size_t)t * D_DIM;
    unsigned short* xbr = xbf + (size_t)t * D_DIM;

    float p[E_NUM];
#pragma unroll
    for (int e = 0; e < E_NUM; ++e) p[e] = 0.f;
#pragma unroll
    for (int c = 0; c < 4; ++c) {
        const int idx = c * 256 + lane * 4;
        const float4 xv = *(const float4*)(xr + idx);
        store4bf(xbr + idx, xv);
#pragma unroll
        for (int e = 0; e < E_NUM; ++e) {
            const float4 gv = *(const float4*)(gw + e * D_DIM + idx);
            p[e] += xv.x * gv.x + xv.y * gv.y + xv.z * gv.z + xv.w * gv.w;
        }
    }
#pragma unroll
    for (int e = 0; e < E_NUM; ++e) {
        float v = p[e];
#pragma unroll
        for (int off = 32; off >= 1; off >>= 1) v += __shfl_xor(v, off);
        p[e] = v;
    }
    if (lane == 0) {
        float mx = p[0];
#pragma unroll
        for (int e = 1; e < E_NUM; ++e) mx = fmaxf(mx, p[e]);
        float pe[E_NUM]; float s = 0.f;
#pragma unroll
        for (int e = 0; e < E_NUM; ++e) { pe[e] = expf(p[e] - mx); s += pe[e]; }
        const float inv = 1.f / s;
        int i0 = 0;
#pragma unroll
        for (int e = 1; e < E_NUM; ++e) if (pe[e] > pe[i0]) i0 = e;
        int i1 = -1;
#pragma unroll
        for (int e = 0; e < E_NUM; ++e) {
            if (e == i0) continue;
            if (i1 < 0 || pe[e] > pe[i1]) i1 = e;
        }
        const float p0 = pe[i0] * inv, p1 = pe[i1] * inv;
        const float wn = 1.f / (p0 + p1 + 1e-9f);
        topi[t * 2 + 0] = i0; topi[t * 2 + 1] = i1;
        topw[t * 2 + 0] = p0 * wn; topw[t * 2 + 1] = p1 * wn;
    }
}

// ---------------------------------------------------------------------------
// Assignment: one block, 16 waves; wave (k,e) scans tokens in order.
// Layout: expert e slots = [k=0: e*CAP2 + 0..CAP) [k=1: e*CAP2+CAP ..).
// cnt[e*2+k] = kept count per (e,k). Pad slots: tok=0, w=0 (masked in down).
// ---------------------------------------------------------------------------
__global__ __launch_bounds__(1024) void assign_k(
    const int* __restrict__ topi, const float* __restrict__ topw,
    int* __restrict__ tok_list, float* __restrict__ w_list,
    int* __restrict__ cnt) {
    __shared__ unsigned char topiL[T_TOK * 2];   // 16 KB
    __shared__ int kept[2][E_NUM];
    const int tid = threadIdx.x;
    const int wid = tid >> 6, lane = tid & 63;
    const int k = wid >> 3, e = wid & 7;
    const uint64_t lt = (1ull << lane) - 1ull;

    for (int i = tid; i < T_TOK * 2 / 4; i += 1024) {
        const int4 v = ((const int4*)topi)[i];
        uchar4 b;
        b.x = (unsigned char)v.x; b.y = (unsigned char)v.y;
        b.z = (unsigned char)v.z; b.w = (unsigned char)v.w;
        ((uchar4*)topiL)[i] = b;
    }
    __syncthreads();

    // phase 1: total per-(k,e) counts
    int total = 0;
    for (int base = 0; base < T_TOK; base += 64) {
        const int idx = topiL[(base + lane) * 2 + k];
        total += __popcll(__ballot(idx == e));
    }
    if (lane == 0) {
        const int kc = min(total, CAP);
        kept[k][e] = kc;
        cnt[e * 2 + k] = kc;
    }
    __syncthreads();
    const int myBase = e * CAP2 + k * CAP;

    // phase 2: ordered compaction of kept tokens
    int running = 0, keptRun = 0;
    for (int base = 0; base < T_TOK; base += 64) {
        const int t = base + lane;
        const bool pred = (topiL[t * 2 + k] == e);
        const uint64_t m = __ballot(pred);
        const int rank = running + __popcll(m & lt);
        const bool keep = pred && (rank < CAP);
        const uint64_t km = __ballot(keep);
        if (keep) {
            const int slot = myBase + keptRun + __popcll(km & lt);
            tok_list[slot] = t;
            w_list[slot] = topw[t * 2 + k];
        }
        running += __popcll(m);
        keptRun += __popcll(km);
    }
    __syncthreads();
    // phase 3: pad unused slots (safe token 0, zero weight)
    for (int s = tid; s < E_NUM * CAP2; s += 1024) {
        const int ee = s / CAP2;
        const int rem = s - ee * CAP2;
        const int kk = rem / CAP, ls = rem - kk * CAP;
        if (ls >= kept[kk][ee]) { tok_list[s] = 0; w_list[s] = 0.f; }
    }
}

// ---------------------------------------------------------------------------
// Fused gate+up GEMM, bf16. BM=128, BN_GU=64 per matrix.
// BK=64 with XOR chunk swizzle: conflict-free ds_read_b128 (round-2/5
// verified: SQ_LDS_BANK_CONFLICT = 0). 32 KB LDS, 4 blocks/CU.
// r9: XCD swizzle REVERTED (r8 measured: FETCH 180->410 MB, dur 180->193,
// MfmaUtil 35.6->32.8). Gateup's B-sharing group (stride-32 ids == same id
// mod 8) is ALREADY XCD-local in the natural mapping, and A-duplication is
// L3-absorbed (unique A ~16 MB << 256 MB). The swizzle destroyed B locality
// (8 MB/expert vs 4 MB L2). Natural mapping is the measured optimum here.
// ---------------------------------------------------------------------------
__global__ __launch_bounds__(256, 4) void gateup_bf_k(
    const unsigned short* __restrict__ xbf,
    const unsigned short* __restrict__ wgbf, const unsigned short* __restrict__ wubf,
    const int* __restrict__ tok_list, const int* __restrict__ cnt,
    unsigned short* __restrict__ h_ws, int e0) {
    const int ez = blockIdx.z;
    const int e = e0 + ez;
    const int kk = blockIdx.y / MT_K;
    const int m0 = (blockIdx.y - kk * MT_K) * BM;
    if (m0 >= cnt[e * 2 + kk]) return;
    const int n0 = blockIdx.x * BN_GU;
    const int sbase = e * CAP2 + kk * CAP + m0;           // global slot base
    const size_t hbase = (size_t)ez * CAP2 + kk * CAP + m0;

    // A: 128x64 (16 KB) | Bg: 64x64 (8 KB) | Bu: 64x64 (8 KB) = 32 KB
    __shared__ __align__(1024) unsigned short smem[16384];

    const int tid = threadIdx.x, wid = tid >> 6, lane = tid & 63;

    const unsigned short* gsrc[8];
    int ldsoff[8];
#pragma unroll
    for (int i = 0; i < 8; ++i) {
        const int f = (wid * 8 + i) * 64 + lane;   // 16B slot index, 0..2047
        const unsigned short* g;
        if (f < 1024) {                  // A: 128 rows x 8 chunks, swizzled
            const int r = f >> 3, c = (f & 7) ^ (r & 7);
            const int tok = tok_list[sbase + r];
            g = xbf + (size_t)tok * D_DIM + c * 8;
        } else if (f < 1536) {           // Bg: 64 rows x 8 chunks, swizzled
            const int fr = f - 1024;
            const int r = fr >> 3, c = (fr & 7) ^ (r & 7);
            g = wgbf + ((size_t)e * H_DIM + n0 + r) * D_DIM + c * 8;
        } else {                         // Bu: 64 rows x 8 chunks, swizzled
            const int fr = f - 1536;
            const int r = fr >> 3, c = (fr & 7) ^ (r & 7);
            g = wubf + ((size_t)e * H_DIM + n0 + r) * D_DIM + c * 8;
        }
        gsrc[i] = g;
        ldsoff[i] = (wid * 8 + i) * 1024;   // bytes, wave-uniform
    }

    float4v accg[4][2], accu[4][2];
#pragma unroll
    for (int i = 0; i < 4; ++i)
#pragma unroll
        for (int jj = 0; jj < 2; ++jj) {
            accg[i][jj] = (float4v){0.f, 0.f, 0.f, 0.f};
            accu[i][jj] = (float4v){0.f, 0.f, 0.f, 0.f};
        }

    const int wm = (wid & 1) * 64;       // wave M-offset: 2 waves over 128 rows
    const int wn = (wid >> 1) * 32;      // wave N-offset: 2 waves over 64 cols
    const int frow = lane & 15;
    const int quad = lane >> 4;

    for (int k0 = 0; k0 < D_DIM; k0 += 64) {
#pragma unroll
        for (int i = 0; i < 8; ++i)
            __builtin_amdgcn_global_load_lds(
                (gu32*)(gsrc[i] + k0),
                (lu32*)((char*)smem + ldsoff[i]), 16, 0, 0);
        __syncthreads();

#pragma unroll
        for (int sp = 0; sp < 2; ++sp) {
            const int c = sp * 4 + quad;          // chunk: k = sp*32 + quad*8
            short8 af[4], bgf[2], buf[2];
#pragma unroll
            for (int i = 0; i < 4; ++i) {
                const int row = wm + i * 16 + frow;
                af[i] = *(const short8*)&smem[(row * 8 + (c ^ (row & 7))) * 8];
            }
#pragma unroll
            for (int jj = 0; jj < 2; ++jj) {
                const int row = wn + jj * 16 + frow;
                bgf[jj] = *(const short8*)&smem[8192 + (row * 8 + (c ^ (row & 7))) * 8];
                buf[jj] = *(const short8*)&smem[12288 + (row * 8 + (c ^ (row & 7))) * 8];
            }
#pragma unroll
            for (int i = 0; i < 4; ++i)
#pragma unroll
                for (int jj = 0; jj < 2; ++jj) {
                    accg[i][jj] = __builtin_amdgcn_mfma_f32_16x16x32_bf16(af[i], bgf[jj], accg[i][jj], 0, 0, 0);
                    accu[i][jj] = __builtin_amdgcn_mfma_f32_16x16x32_bf16(af[i], buf[jj], accu[i][jj], 0, 0, 0);
                }
        }
        __syncthreads();
    }

    const int col = lane & 15, rbase = (lane >> 4) * 4;
#pragma unroll
    for (int i = 0; i < 4; ++i)
#pragma unroll
        for (int jj = 0; jj < 2; ++jj)
#pragma unroll
            for (int r = 0; r < 4; ++r) {
                const float g = accg[i][jj][r];
                const float u = accu[i][jj][r];
                const float hv = (g / (1.f + __expf(-g))) * u;
                const int m = wm + i * 16 + rbase + r;
                const int n = wn + jj * 16 + col;
                h_ws[(hbase + m) * H_DIM + (n0 + n)] = f2bf(hv);
            }
}

// ---------------------------------------------------------------------------
// Down GEMM, SPLIT-BUFFER merged form, 3 blocks/CU, WITH bijective XCD
// swizzle (KEPT from r8: down's A-sharing group IS id-consecutive; the
// swizzle removed the 8x h-panel duplication — ~-21 µs attributed by
// subtraction in r8, consistent with r7's FETCH 450 MB diagnosis).
// kk=0 -> out, kk=1 -> out2 (both pre-zeroed), no atomics; combine_k adds.
// ---------------------------------------------------------------------------
__global__ __launch_bounds__(256, 3) void down_split_bf_k(
    const unsigned short* __restrict__ h_ws, const unsigned short* __restrict__ wdbf,
    const int* __restrict__ tok_list, const float* __restrict__ w_list,
    const int* __restrict__ cnt, float* __restrict__ out,
    float* __restrict__ out2, int e0) {
    // ---- XCD swizzle: remap dispatch-order id j -> work id s ----
    const int nwg = 80 * gridDim.z;                  // 8 * 10 * 2ne
    const int j = blockIdx.x + (blockIdx.y << 3) + blockIdx.z * 80;
    const int s = (j & 7) * (nwg >> 3) + (j >> 3);
    const int bx = s & 7;                            // n-tile (8)
    const int t2 = s >> 3;
    const int by = t2 % 10;                          // m-tile (10)
    const int zz = t2 / 10;                          // region (2ne)

    const int ez = zz >> 1;
    const int kk = zz & 1;
    const int e = e0 + ez;
    const int m0 = by * BM;
    const int nkept = cnt[e * 2 + kk];
    if (m0 >= nkept) return;
    const int n0 = bx * BN;
    const int sbase = e * CAP2 + kk * CAP + m0;
    const size_t hbase = (size_t)ez * CAP2 + kk * CAP + m0;

    __shared__ __align__(1024) unsigned short smem[16384];   // 32 KB: A|B
    __shared__ int tokL[BM];
    __shared__ float wL[BM];

    const int tid = threadIdx.x, wid = tid >> 6, lane = tid & 63;
    if (tid < BM) {
        tokL[tid] = tok_list[sbase + tid];
        wL[tid] = w_list[sbase + tid];
    }

    const unsigned short* gsrc[8];
    int ldsoff[8];
#pragma unroll
    for (int i = 0; i < 8; ++i) {
        const int f = (wid * 8 + i) * 64 + lane;   // 16B slot index, 0..2047
        const unsigned short* g;
        if (f < 1024) {          // A region: h rows, 128 rows x 8 chunks
            const int r = f >> 3, c = (f & 7) ^ (r & 7);
            g = h_ws + (hbase + r) * H_DIM + c * 8;
        } else {                 // B region: wd rows
            const int fr = f - 1024;
            const int r = fr >> 3, c = (fr & 7) ^ (r & 7);
            g = wdbf + ((size_t)e * D_DIM + n0 + r) * H_DIM + c * 8;
        }
        gsrc[i] = g;
        ldsoff[i] = (wid * 8 + i) * 1024;   // bytes, wave-uniform
    }

    float4v acc[4][4];
#pragma unroll
    for (int i = 0; i < 4; ++i)
#pragma unroll
        for (int jj = 0; jj < 4; ++jj) acc[i][jj] = (float4v){0.f, 0.f, 0.f, 0.f};

    const int wm = (wid & 1) * 64, wn = (wid >> 1) * 64;
    const int frow = lane & 15;
    const int quad = lane >> 4;

    for (int k0 = 0; k0 < H_DIM; k0 += 64) {
#pragma unroll
        for (int i = 0; i < 8; ++i)
            __builtin_amdgcn_global_load_lds(
                (gu32*)(gsrc[i] + k0),
                (lu32*)((char*)smem + ldsoff[i]), 16, 0, 0);
        __syncthreads();

#pragma unroll
        for (int sp = 0; sp < 2; ++sp) {
            const int c = sp * 4 + quad;
            short8 af[4], bf[4];
#pragma unroll
            for (int i = 0; i < 4; ++i) {
                const int row = wm + i * 16 + frow;
                af[i] = *(const short8*)&smem[(row * 8 + (c ^ (row & 7))) * 8];
            }
#pragma unroll
            for (int jj = 0; jj < 4; ++jj) {
                const int row = wn + jj * 16 + frow;
                bf[jj] = *(const short8*)&smem[8192 + (row * 8 + (c ^ (row & 7))) * 8];
            }
#pragma unroll
            for (int i = 0; i < 4; ++i)
#pragma unroll
                for (int jj = 0; jj < 4; ++jj)
                    acc[i][jj] = __builtin_amdgcn_mfma_f32_16x16x32_bf16(af[i], bf[jj], acc[i][jj], 0, 0, 0);
        }
        __syncthreads();
    }

    // Epilogue: plain stores to the kk-selected buffer; pad rows masked.
    float* dbuf = kk ? out2 : out;
    const int col = lane & 15, rbase = (lane >> 4) * 4;
#pragma unroll
    for (int i = 0; i < 4; ++i)
#pragma unroll
        for (int r = 0; r < 4; ++r) {
            const int m = wm + i * 16 + rbase + r;
            if (m0 + m >= nkept) continue;       // pad row: skip
            const float wRow = wL[m];
            float* orow = dbuf + (size_t)tokL[m] * D_DIM + n0;
#pragma unroll
            for (int jj = 0; jj < 4; ++jj) {
                const int n = jj * 16 + wn + col;
                orow[n] = acc[i][jj][r] * wRow;
            }
        }
}

// combine: out += out2 (float4 grid-stride, ~100 MB traffic)
__global__ __launch_bounds__(256) void combine_k(
    float* __restrict__ out, const float* __restrict__ out2) {
    const int total = T_TOK * D_DIM / 4;   // 2,097,152 float4s
    const int stride = gridDim.x * 256;
    for (int i = blockIdx.x * 256 + threadIdx.x; i < total; i += stride) {
        float4 a = ((float4*)out)[i];
        const float4 b = ((const float4*)out2)[i];
        a.x += b.x; a.y += b.y; a.z += b.z; a.w += b.w;
        ((float4*)out)[i] = a;
    }
}

// ---------------------------------------------------------------------------
// Down GEMM two-pass form (round-5 verified fallback when out2 doesn't fit).
// Pass kk=0: plain stores. Pass kk=1: load-add-store. Pad rows masked.
// ---------------------------------------------------------------------------
__global__ __launch_bounds__(256, 3) void down_bf_k(
    const unsigned short* __restrict__ h_ws, const unsigned short* __restrict__ wdbf,
    const int* __restrict__ tok_list, const float* __restrict__ w_list,
    const int* __restrict__ cnt, float* __restrict__ out, int e0, int kk) {
    const int ez = blockIdx.z;
    const int e = e0 + ez;
    const int m0 = blockIdx.y * BM;
    const int nkept = cnt[e * 2 + kk];
    if (m0 >= nkept) return;
    const int n0 = blockIdx.x * BN;
    const int sbase = e * CAP2 + kk * CAP + m0;
    const size_t hbase = (size_t)ez * CAP2 + kk * CAP + m0;

    __shared__ __align__(1024) unsigned short smem[16384];   // 32 KB: A|B
    __shared__ int tokL[BM];
    __shared__ float wL[BM];

    const int tid = threadIdx.x, wid = tid >> 6, lane = tid & 63;
    if (tid < BM) {
        tokL[tid] = tok_list[sbase + tid];
        wL[tid] = w_list[sbase + tid];
    }

    const unsigned short* gsrc[8];
    int ldsoff[8];
#pragma unroll
    for (int i = 0; i < 8; ++i) {
        const int f = (wid * 8 + i) * 64 + lane;   // 16B slot index, 0..2047
        const unsigned short* g;
        if (f < 1024) {          // A region: h rows, 128 rows x 8 chunks
            const int r = f >> 3, c = (f & 7) ^ (r & 7);
            g = h_ws + (hbase + r) * H_DIM + c * 8;
        } else {                 // B region: wd rows
            const int fr = f - 1024;
            const int r = fr >> 3, c = (fr & 7) ^ (r & 7);
            g = wdbf + ((size_t)e * D_DIM + n0 + r) * H_DIM + c * 8;
        }
        gsrc[i] = g;
        ldsoff[i] = (wid * 8 + i) * 1024;   // bytes, wave-uniform
    }

    float4v acc[4][4];
#pragma unroll
    for (int i = 0; i < 4; ++i)
#pragma unroll
        for (int j = 0; j < 4; ++j) acc[i][j] = (float4v){0.f, 0.f, 0.f, 0.f};

    const int wm = (wid & 1) * 64, wn = (wid >> 1) * 64;
    const int frow = lane & 15;
    const int quad = lane >> 4;

    for (int k0 = 0; k0 < H_DIM; k0 += 64) {
#pragma unroll
        for (int i = 0; i < 8; ++i)
            __builtin_amdgcn_global_load_lds(
                (gu32*)(gsrc[i] + k0),
                (lu32*)((char*)smem + ldsoff[i]), 16, 0, 0);
        __syncthreads();

#pragma unroll
        for (int s = 0; s < 2; ++s) {
            const int c = s * 4 + quad;
            short8 af[4], bf[4];
#pragma unroll
            for (int i = 0; i < 4; ++i) {
                const int row = wm + i * 16 + frow;
                af[i] = *(const short8*)&smem[(row * 8 + (c ^ (row & 7))) * 8];
            }
#pragma unroll
            for (int j = 0; j < 4; ++j) {
                const int row = wn + j * 16 + frow;
                bf[j] = *(const short8*)&smem[8192 + (row * 8 + (c ^ (row & 7))) * 8];
            }
#pragma unroll
            for (int i = 0; i < 4; ++i)
#pragma unroll
                for (int j = 0; j < 4; ++j)
                    acc[i][j] = __builtin_amdgcn_mfma_f32_16x16x32_bf16(af[i], bf[j], acc[i][j], 0, 0, 0);
        }
        __syncthreads();
    }

    // Epilogue: plain store (kk=0) or load-add-store (kk=1); pad rows masked.
    const int col = lane & 15, rbase = (lane >> 4) * 4;
#pragma unroll
    for (int i = 0; i < 4; ++i)
#pragma unroll
        for (int r = 0; r < 4; ++r) {
            const int m = wm + i * 16 + rbase + r;
            if (m0 + m >= nkept) continue;       // pad row: skip (avoid races)
            const float wRow = wL[m];
            float* orow = out + (size_t)tokL[m] * D_DIM + n0;
#pragma unroll
            for (int j = 0; j < 4; ++j) {
                const int n = j * 16 + wn + col;
                const float v = acc[i][j][r] * wRow;
                if (kk == 0) orow[n] = v;
                else         orow[n] += v;
            }
        }
}

// ---------------------------------------------------------------------------
// Legacy fp32-staging kernels (fallback if workspace too small for bf16 path)
// ---------------------------------------------------------------------------
__global__ __launch_bounds__(256, 2) void gateup_legacy_k(
    const float* __restrict__ x,
    const float* __restrict__ wg_all, const float* __restrict__ wu_all,
    const int* __restrict__ tok_list, const int* __restrict__ cnt,
    unsigned short* __restrict__ h_ws, int e0) {
    const int ez = blockIdx.z;
    const int e = e0 + ez;
    const int kk = blockIdx.y / MT_K;
    const int m0 = (blockIdx.y - kk * MT_K) * BM;
    if (m0 >= cnt[e * 2 + kk]) return;
    const int n0 = blockIdx.x * BN;
    const int sbase = e * CAP2 + kk * CAP + m0;
    const size_t hbase = (size_t)ez * CAP2 + kk * CAP + m0;

    __shared__ __align__(16) unsigned short As[BM][BK];
    __shared__ __align__(16) unsigned short Bg[BN][BK];
    __shared__ __align__(16) unsigned short Bu[BN][BK];
    __shared__ int tokL[BM];

    const int tid = threadIdx.x;
    if (tid < BM) tokL[tid] = tok_list[sbase + tid];
    __syncthreads();

    const float* wg = wg_all + (size_t)e * H_DIM * D_DIM;
    const float* wu = wu_all + (size_t)e * H_DIM * D_DIM;

    const float* aSrc[4]; const float* gSrc[4]; const float* uSrc[4];
    unsigned short* aDst[4]; unsigned short* gDst[4]; unsigned short* uDst[4];
#pragma unroll
    for (int it = 0; it < 4; ++it) {
        const int fid = it * 256 + tid;
        const int row = fid >> 3;
        const int c4 = (fid & 7) * 4;
        aSrc[it] = x + (size_t)tokL[row] * D_DIM + c4;
        gSrc[it] = wg + (size_t)(n0 + row) * D_DIM + c4;
        uSrc[it] = wu + (size_t)(n0 + row) * D_DIM + c4;
        aDst[it] = &As[row][c4];
        gDst[it] = &Bg[row][c4];
        uDst[it] = &Bu[row][c4];
    }

    float4v accg[4][4], accu[4][4];
#pragma unroll
    for (int i = 0; i < 4; ++i)
#pragma unroll
        for (int j = 0; j < 4; ++j) {
            accg[i][j] = (float4v){0.f, 0.f, 0.f, 0.f};
            accu[i][j] = (float4v){0.f, 0.f, 0.f, 0.f};
        }

    const int wid = tid >> 6, lane = tid & 63;
    const int wm = (wid & 1) * 64, wn = (wid >> 1) * 64;
    const int frow = lane & 15;
    const int fk = (lane >> 4) * 8;

    for (int k0 = 0; k0 < D_DIM; k0 += BK) {
#pragma unroll
        for (int it = 0; it < 4; ++it) {
            store4bf(aDst[it], *(const float4*)(aSrc[it] + k0));
            store4bf(gDst[it], *(const float4*)(gSrc[it] + k0));
            store4bf(uDst[it], *(const float4*)(uSrc[it] + k0));
        }
        __syncthreads();
        short8 af[4], bgf[4], buf[4];
#pragma unroll
        for (int i = 0; i < 4; ++i)
            af[i] = *(const short8*)&As[wm + i * 16 + frow][fk];
#pragma unroll
        for (int j = 0; j < 4; ++j) {
            bgf[j] = *(const short8*)&Bg[wn + j * 16 + frow][fk];
            buf[j] = *(const short8*)&Bu[wn + j * 16 + frow][fk];
        }
#pragma unroll
        for (int i = 0; i < 4; ++i)
#pragma unroll
            for (int j = 0; j < 4; ++j) {
                accg[i][j] = __builtin_amdgcn_mfma_f32_16x16x32_bf16(af[i], bgf[j], accg[i][j], 0, 0, 0);
                accu[i][j] = __builtin_amdgcn_mfma_f32_16x16x32_bf16(af[i], buf[j], accu[i][j], 0, 0, 0);
            }
        __syncthreads();
    }

    const int col = lane & 15, rbase = (lane >> 4) * 4;
#pragma unroll
    for (int i = 0; i < 4; ++i)
#pragma unroll
        for (int j = 0; j < 4; ++j)
#pragma unroll
            for (int r = 0; r < 4; ++r) {
                const float g = accg[i][j][r];
                const float u = accu[i][j][r];
                const float hv = (g / (1.f + __expf(-g))) * u;
                const int m = wm + i * 16 + rbase + r;
                const int n = wn + j * 16 + col;
                h_ws[(hbase + m) * H_DIM + (n0 + n)] = f2bf(hv);
            }
}

__global__ __launch_bounds__(256, 2) void down_legacy_k(
    const unsigned short* __restrict__ h_ws, const float* __restrict__ wd_all,
    const int* __restrict__ tok_list, const float* __restrict__ w_list,
    const int* __restrict__ cnt, float* __restrict__ out, int e0) {
    const int ez = blockIdx.z;
    const int e = e0 + ez;
    const int kk = blockIdx.y / MT_K;
    const int m0 = (blockIdx.y - kk * MT_K) * BM;
    if (m0 >= cnt[e * 2 + kk]) return;
    const int n0 = blockIdx.x * BN;
    const int sbase = e * CAP2 + kk * CAP + m0;
    const size_t hbase = (size_t)ez * CAP2 + kk * CAP + m0;

    __shared__ __align__(16) unsigned short As[BM][BK];
    __shared__ __align__(16) unsigned short Bs[BN][BK];
    __shared__ int tokL[BM];
    __shared__ float wL[BM];

    const int tid = threadIdx.x;
    if (tid < BM) {
        tokL[tid] = tok_list[sbase + tid];
        wL[tid] = w_list[sbase + tid];
    }
    __syncthreads();

    const unsigned short* hA = h_ws + hbase * H_DIM;
    const float* wd = wd_all + (size_t)e * D_DIM * H_DIM;

    const unsigned short* aSrc[2]; unsigned short* aDst[2];
#pragma unroll
    for (int it = 0; it < 2; ++it) {
        const int fid = it * 256 + tid;
        const int row = fid >> 2;
        const int c8 = (fid & 3) * 8;
        aSrc[it] = hA + (size_t)row * H_DIM + c8;
        aDst[it] = &As[row][c8];
    }
    const float* bSrc[4]; unsigned short* bDst[4];
#pragma unroll
    for (int it = 0; it < 4; ++it) {
        const int fid = it * 256 + tid;
        const int row = fid >> 3;
        const int c4 = (fid & 7) * 4;
        bSrc[it] = wd + (size_t)(n0 + row) * H_DIM + c4;
        bDst[it] = &Bs[row][c4];
    }

    float4v acc[4][4];
#pragma unroll
    for (int i = 0; i < 4; ++i)
#pragma unroll
        for (int j = 0; j < 4; ++j) acc[i][j] = (float4v){0.f, 0.f, 0.f, 0.f};

    const int wid = tid >> 6, lane = tid & 63;
    const int wm = (wid & 1) * 64, wn = (wid >> 1) * 64;
    const int frow = lane & 15;
    const int fk = (lane >> 4) * 8;

    for (int k0 = 0; k0 < H_DIM; k0 += BK) {
#pragma unroll
        for (int it = 0; it < 2; ++it)
            *(uint4*)aDst[it] = *(const uint4*)(aSrc[it] + k0);
#pragma unroll
        for (int it = 0; it < 4; ++it)
            store4bf(bDst[it], *(const float4*)(bSrc[it] + k0));
        __syncthreads();
        short8 af[4], bf[4];
#pragma unroll
        for (int i = 0; i < 4; ++i)
            af[i] = *(const short8*)&As[wm + i * 16 + frow][fk];
#pragma unroll
        for (int j = 0; j < 4; ++j)
            bf[j] = *(const short8*)&Bs[wn + j * 16 + frow][fk];
#pragma unroll
        for (int i = 0; i < 4; ++i)
#pragma unroll
            for (int j = 0; j < 4; ++j)
                acc[i][j] = __builtin_amdgcn_mfma_f32_16x16x32_bf16(af[i], bf[j], acc[i][j], 0, 0, 0);
        __syncthreads();
    }

    const int col = lane & 15, rbase = (lane >> 4) * 4;
#pragma unroll
    for (int i = 0; i < 4; ++i)
#pragma unroll
        for (int j = 0; j < 4; ++j)
#pragma unroll
            for (int r = 0; r < 4; ++r) {
                const int m = wm + i * 16 + rbase + r;
                const int n = wn + j * 16 + col;
                const float v = acc[i][j][r] * wL[m];
                unsafeAtomicAdd(&out[(size_t)tokL[m] * D_DIM + n0 + n], v);
            }
}

// ---------------------------------------------------------------------------
extern "C" void kernel_launch(void* const* d_in, const int* in_sizes, int n_in,
                              void* d_out, int out_size, void* d_ws, size_t ws_size,
                              hipStream_t stream) {
    const float* x        = (const float*)d_in[0];
    const float* gate_w   = (const float*)d_in[1];
    const float* gate_pw  = (const float*)d_in[2];
    const float* up_pw    = (const float*)d_in[3];
    const float* down_pw  = (const float*)d_in[4];
    float* out = (float*)d_out;
    (void)n_in; (void)in_sizes; (void)out_size;

    uint8_t* ws = (uint8_t*)d_ws;
    size_t off = 0;
    int*   topi     = (int*)(ws + off);   off += (size_t)T_TOK * 2 * 4;
    float* topw     = (float*)(ws + off); off += (size_t)T_TOK * 2 * 4;
    int*   tok_list = (int*)(ws + off);   off += (size_t)E_NUM * CAP2 * 4;
    float* w_list   = (float*)(ws + off); off += (size_t)E_NUM * CAP2 * 4;
    int*   cnt      = (int*)(ws + off);   off += 256;
    off = (off + 4095) & ~(size_t)4095;
    const size_t routing_end = off;

    const size_t x_elems = (size_t)T_TOK * D_DIM;           // 8.4 M
    const size_t w_elems = (size_t)E_NUM * H_DIM * D_DIM;   // 16.8 M each
    unsigned short* xbf  = (unsigned short*)(ws + off); off += x_elems * 2;
    unsigned short* wgbf = (unsigned short*)(ws + off); off += w_elems * 2;
    unsigned short* wubf = (unsigned short*)(ws + off); off += w_elems * 2;
    unsigned short* wdbf = (unsigned short*)(ws + off); off += w_elems * 2;
    const size_t need_base = off;                           // ~118 MB
    const size_t out2_sz = (size_t)T_TOK * D_DIM * 4;       // 33.5 MB
    const size_t per_e = (size_t)CAP2 * H_DIM * 2;          // 10.5 MB / expert

    hipMemsetAsync(out, 0, (size_t)T_TOK * D_DIM * sizeof(float), stream);

    if (ws_size >= need_base + out2_sz + per_e) {
        // bf16 fast path with split-buffer merged down
        float* out2 = (float*)(ws + need_base);
        unsigned short* h_ws = (unsigned short*)(ws + need_base + out2_sz);
        int chunk = (int)((ws_size - need_base - out2_sz) / per_e);
        if (chunk > E_NUM) chunk = E_NUM;

        hipMemsetAsync(out2, 0, out2_sz, stream);
        prep_k<<<ROUTE_BLKS + CONV_BLKS, 256, 0, stream>>>(
            x, gate_w, topi, topw, xbf,
            gate_pw, up_pw, down_pw, wgbf, wubf, wdbf);
        assign_k<<<1, 1024, 0, stream>>>(topi, topw, tok_list, w_list, cnt);

        for (int e0 = 0; e0 < E_NUM; e0 += chunk) {
            const int ne = (e0 + chunk <= E_NUM) ? chunk : (E_NUM - e0);
            dim3 g1(H_DIM / BN_GU, 2 * MT_K, ne);
            gateup_bf_k<<<g1, 256, 0, stream>>>(xbf, wgbf, wubf, tok_list, cnt, h_ws, e0);
            dim3 g2(D_DIM / BN, MT_K, 2 * ne);
            down_split_bf_k<<<g2, 256, 0, stream>>>(h_ws, wdbf, tok_list, w_list,
                                                    cnt, out, out2, e0);
        }
        combine_k<<<2048, 256, 0, stream>>>(out, out2);
    } else if (ws_size >= need_base + per_e) {
        // bf16 path, two-pass down (round-5 verified) when out2 doesn't fit
        unsigned short* h_ws = (unsigned short*)(ws + need_base);
        int chunk = (int)((ws_size - need_base) / per_e);
        if (chunk > E_NUM) chunk = E_NUM;

        prep_k<<<ROUTE_BLKS + CONV_BLKS, 256, 0, stream>>>(
            x, gate_w, topi, topw, xbf,
            gate_pw, up_pw, down_pw, wgbf, wubf, wdbf);
        assign_k<<<1, 1024, 0, stream>>>(topi, topw, tok_list, w_list, cnt);

        for (int e0 = 0; e0 < E_NUM; e0 += chunk) {
            const int ne = (e0 + chunk <= E_NUM) ? chunk : (E_NUM - e0);
            dim3 g1(H_DIM / BN_GU, 2 * MT_K, ne);
            gateup_bf_k<<<g1, 256, 0, stream>>>(xbf, wgbf, wubf, tok_list, cnt, h_ws, e0);
            dim3 g2(D_DIM / BN, MT_K, ne);
            down_bf_k<<<g2, 256, 0, stream>>>(h_ws, wdbf, tok_list, w_list, cnt, out, e0, 0);
            down_bf_k<<<g2, 256, 0, stream>>>(h_ws, wdbf, tok_list, w_list, cnt, out, e0, 1);
        }
    } else {
        // legacy fp32-staging path (small workspace)
        unsigned short* h_ws = (unsigned short*)(ws + routing_end);
        int chunk = (ws_size > routing_end) ? (int)((ws_size - routing_end) / per_e) : 0;
        if (chunk > E_NUM) chunk = E_NUM;
        if (chunk < 1) chunk = 1;

        router_k<<<T_TOK / 4, 256, 0, stream>>>(x, gate_w, topi, topw, xbf);
        assign_k<<<1, 1024, 0, stream>>>(topi, topw, tok_list, w_list, cnt);

        for (int e0 = 0; e0 < E_NUM; e0 += chunk) {
            const int ne = (e0 + chunk <= E_NUM) ? chunk : (E_NUM - e0);
            dim3 g1(H_DIM / BN, 2 * MT_K, ne);
            gateup_legacy_k<<<g1, 256, 0, stream>>>(x, gate_pw, up_pw, tok_list, cnt, h_ws, e0);
            dim3 g2(D_DIM / BN, 2 * MT_K, ne);
            down_legacy_k<<<g2, 256, 0, stream>>>(h_ws, down_pw, tok_list, w_list, cnt, out, e0);
        }
    }
}